// Round 15
// baseline (131.401 us; speedup 1.0000x reference)
//
#include <hip/hip_runtime.h>
#include <hip/hip_bf16.h>

#define B_ 4
#define C_ 256
#define S_ 4096
#define NH_ 4
#define HD_ 64
#define LOG2E 1.4426950408889634f
#define QSC 0.18033688011112042f  // 0.125 * log2(e), folded into W_q

typedef __attribute__((ext_vector_type(8))) short short8;
typedef __attribute__((ext_vector_type(4))) short short4v;
typedef __attribute__((ext_vector_type(4))) float f32x4;
typedef __attribute__((ext_vector_type(16))) float f32x16;
typedef __attribute__((ext_vector_type(4))) unsigned uint4v;

static __device__ __forceinline__ short f2bf(float f) {
  unsigned u = __builtin_bit_cast(unsigned, f);
  u += 0x7fffu + ((u >> 16) & 1u);
  return (short)(u >> 16);
}
static __device__ __forceinline__ float bf2f(short h) {
  unsigned u = ((unsigned)(unsigned short)h) << 16;
  return __builtin_bit_cast(float, u);
}

#if __has_builtin(__builtin_amdgcn_exp2f)
#define EXP2(x) __builtin_amdgcn_exp2f(x)
#else
#define EXP2(x) exp2f(x)
#endif

static __device__ __forceinline__ unsigned pkbf(float a, float b) {
  unsigned r;
  asm("v_cvt_pk_bf16_f32 %0, %1, %2" : "=v"(r) : "v"(a), "v"(b));
  return r;
}
static __device__ __forceinline__ void pl32swap(unsigned& a, unsigned& b) {
  asm volatile("v_permlane32_swap_b32 %0, %1" : "+v"(a), "+v"(b));
}
// async global->LDS, 16B per lane; lds dest = wave-uniform base + lane*16
static __device__ __forceinline__ void gl_lds16(const short* g, char* l) {
  __builtin_amdgcn_global_load_lds(
      (const __attribute__((address_space(1))) void*)g,
      (__attribute__((address_space(3))) void*)l, 16, 0, 0);
}

// ---------------- k_pre: GroupNorm partial sums + weight convert ------------
__global__ __launch_bounds__(256) void k_pre(const float* __restrict__ x,
                                             const float* __restrict__ wq,
                                             const float* __restrict__ wp,
                                             float* __restrict__ part,
                                             short* __restrict__ oq,
                                             short* __restrict__ op) {
  int t = threadIdx.x;
  const float* p = x + (size_t)blockIdx.x * 16384;
  float s = 0.f, ss = 0.f;
  const float4* p4 = reinterpret_cast<const float4*>(p);
  for (int i = t; i < 4096; i += 256) {
    float4 v = p4[i];
    s += v.x + v.y + v.z + v.w;
    ss += v.x * v.x + v.y * v.y + v.z * v.z + v.w * v.w;
  }
  for (int m = 1; m < 64; m <<= 1) {
    s += __shfl_xor(s, m, 64);
    ss += __shfl_xor(ss, m, 64);
  }
  __shared__ float rs[4], rss[4];
  int w = t >> 6;
  if ((t & 63) == 0) { rs[w] = s; rss[w] = ss; }
  {
    int i = (blockIdx.x * 256 + t) * 4;
    const int n1 = 768 * 256;
    float sc = 1.f;
    const float* src;
    short* dst;
    if (i < n1) {
      src = wq + i; dst = oq + i;
      if (i < 256 * 256) sc = QSC;
    } else {
      src = wp + (i - n1); dst = op + (i - n1);
    }
    float4 v = *reinterpret_cast<const float4*>(src);
    short4v o;
    o[0] = f2bf(v.x * sc); o[1] = f2bf(v.y * sc);
    o[2] = f2bf(v.z * sc); o[3] = f2bf(v.w * sc);
    *reinterpret_cast<short4v*>(dst) = o;
  }
  __syncthreads();
  if (t == 0) {
    part[2 * blockIdx.x] = rs[0] + rs[1] + rs[2] + rs[3];
    part[2 * blockIdx.x + 1] = rss[0] + rss[1] + rss[2] + rss[3];
  }
}

// ---------------- GEMM (TN, bf16 MFMA) ----------------
// A staged via gl_lds (swizzled [128][64B]); B staged via ds_write into padded
// [128][40] layout.
// MODE 0: qkv — B-tile built on the fly from x with GroupNorm applied
//   (fuses the old gn_apply kernel; stats finalized from part[] in-block).
// MODE 1: proj — B-tile built as (sum_i op_i)/(sum_i l_i).
template <int MODE, int NSP>
__global__ __launch_bounds__(256) void k_gemm(const short* __restrict__ Wbf,
                                              const float* __restrict__ xgn,
                                              const float* __restrict__ gw,
                                              const float* __restrict__ gb,
                                              const float* __restrict__ part,
                                              const short* __restrict__ Xt,
                                              const float* __restrict__ bias,
                                              const float* __restrict__ xres,
                                              short* __restrict__ q_sd,
                                              short* __restrict__ k_sd,
                                              short* __restrict__ v_ds,
                                              long op_stride,
                                              const float* __restrict__ lbufg,
                                              float* __restrict__ outp) {
  int tn = blockIdx.x;
  int tm = blockIdx.y;
  int b = blockIdx.z;
  int t = threadIdx.x;
  __shared__ short lds[4 * 64 * 72];  // [0,8K)=Al, [8K,18.4K)=Blp, epilogue reuse
  __shared__ float gnA[256], gnB[256];
  __shared__ float smu[8], sri[8];
  char* Al = (char*)lds;
  short* Blp = lds + 4096;  // padded B base (shorts), [128][40]
  int w = t >> 6, lane = t & 63;
  int wr = w >> 1, wc = w & 1;
  int l15 = lane & 15, l4 = lane >> 4;
  int wbg = __builtin_amdgcn_readfirstlane(w) << 10;

  if (MODE == 0) {
    // finalize GN stats and build per-channel affine (A, B) tables
    if (t < 8) {
      int base = b * 64 + t * 8;
      float s = 0.f, ss = 0.f;
      for (int j = 0; j < 8; j++) {
        s += part[2 * (base + j)];
        ss += part[2 * (base + j) + 1];
      }
      float inv = 1.f / (32.f * S_);
      float mu = s * inv;
      float var = ss * inv - mu * mu;
      smu[t] = mu;
      sri[t] = rsqrtf(var + 1e-5f);
    }
    __syncthreads();
    {
      float ri = sri[t >> 5], mu = smu[t >> 5];
      float A = gw[t] * ri;
      gnA[t] = A;
      gnB[t] = gb[t] - mu * A;
    }
  }

  f32x4 acc[4][4];
  for (int m = 0; m < 4; m++)
    for (int n = 0; n < 4; n++)
      for (int j = 0; j < 4; j++) acc[m][n][j] = 0.f;

  const short* Arow = Wbf + (size_t)(tm * 128) * 256;

  // A staging source offsets (pre-swizzled): slot s -> r=s>>2, c=s&3,
  // global chunk = c ^ ((r>>1)&3)
  int r0 = t >> 2, c40 = t & 3;
  int sw0 = (c40 ^ ((r0 >> 1) & 3)) * 8;       // shorts
  int r1 = (t + 256) >> 2;
  int sw1 = (c40 ^ ((r1 >> 1) & 3)) * 8;

  for (int kk = 0; kk < 256; kk += 32) {
    __syncthreads();  // previous tile fully consumed (also covers gnA/gnB init)
    gl_lds16(Arow + (size_t)r0 * 256 + kk + sw0, Al + wbg);
    gl_lds16(Arow + (size_t)r1 * 256 + kk + sw1, Al + 4096 + wbg);
    for (int i = 0; i < 2; i++) {
      int cch = t + i * 256;
      int r = cch >> 2, c4 = cch & 3;
      short8 vbv;
      if (MODE == 0) {
        int cb = kk + c4 * 8;
        const float* xp = xgn + ((size_t)(b * C_ + cb)) * S_ + tn * 128 + r;
#pragma unroll
        for (int j = 0; j < 8; j++)
          vbv[j] = f2bf(xp[(size_t)j * S_] * gnA[cb + j] + gnB[cb + j]);
      } else {
        int c = kk + c4 * 8;
        int bh2 = b * 4 + (c >> 6);
        int d = c & 63;
        int s_glob = tn * 128 + r;
        size_t ro = ((size_t)bh2 * S_ + s_glob) * HD_ + d;
        float a8[8] = {0.f, 0.f, 0.f, 0.f, 0.f, 0.f, 0.f, 0.f};
        float l = 0.f;
#pragma unroll
        for (int i2 = 0; i2 < NSP; i2++) {
          short8 pv = *reinterpret_cast<const short8*>(Xt + (size_t)i2 * op_stride + ro);
#pragma unroll
          for (int j = 0; j < 8; j++) a8[j] += bf2f(pv[j]);
          l += lbufg[(size_t)(i2 * 16 + bh2) * S_ + s_glob];
        }
        float inv = 1.f / l;
#pragma unroll
        for (int j = 0; j < 8; j++) vbv[j] = f2bf(a8[j] * inv);
      }
      *reinterpret_cast<short8*>(&Blp[r * 40 + c4 * 8]) = vbv;
    }
    asm volatile("s_waitcnt vmcnt(0)" ::: "memory");
    __syncthreads();

    short8 af[4], bf[4];
    for (int mt = 0; mt < 4; mt++) {
      int row = wr * 64 + mt * 16 + l15;
      af[mt] = *reinterpret_cast<short8*>(Al + row * 64 + ((l4 ^ ((row >> 1) & 3)) << 4));
    }
    for (int nt = 0; nt < 4; nt++) {
      int row = wc * 64 + nt * 16 + l15;
      bf[nt] = *reinterpret_cast<short8*>(&Blp[row * 40 + l4 * 8]);
    }
    for (int mt = 0; mt < 4; mt++)
      for (int nt = 0; nt < 4; nt++)
        acc[mt][nt] = __builtin_amdgcn_mfma_f32_16x16x32_bf16(af[mt], bf[nt], acc[mt][nt], 0, 0, 0);
  }
  __syncthreads();

  if (MODE == 0) {
    int o_base = tm * 128 + wr * 64;
    int tt = o_base >> 8;
    int h = (o_base >> 6) & 3;
    int s_base = tn * 128 + wc * 64;
    int bh = b * NH_ + h;
    if (tt == 2) {
      for (int mt = 0; mt < 4; mt++)
        for (int nt = 0; nt < 4; nt++)
          for (int i = 0; i < 4; i++) {
            int o = o_base + mt * 16 + l4 * 4 + i;
            int dd = o & 63;
            int s = s_base + nt * 16 + l15;
            float val = acc[mt][nt][i] + bias[o];
            v_ds[((size_t)bh * HD_ + dd) * S_ + s] = f2bf(val);
          }
    } else {
      float bsc = (tt == 0) ? QSC : 1.f;  // q bias scaled like W_q
      short* T = lds + w * (64 * 72);
      for (int mt = 0; mt < 4; mt++)
        for (int nt = 0; nt < 4; nt++)
          for (int i = 0; i < 4; i++) {
            int o = o_base + mt * 16 + l4 * 4 + i;
            int dd = mt * 16 + l4 * 4 + i;
            int sl = nt * 16 + l15;
            float val = acc[mt][nt][i] + bias[o] * bsc;
            T[sl * 72 + dd] = f2bf(val);
          }
      short* dst = (tt == 0) ? q_sd : k_sd;
      for (int it = 0; it < 8; it++) {
        int cch = lane + it * 64;
        int sl = cch >> 3, c8 = cch & 7;
        short8 v = *reinterpret_cast<short8*>(&T[sl * 72 + c8 * 8]);
        *reinterpret_cast<short8*>(dst + ((size_t)bh * S_ + s_base + sl) * HD_ + c8 * 8) = v;
      }
    }
  } else {
    for (int mt = 0; mt < 4; mt++) {
      int o = tm * 128 + wr * 64 + mt * 16 + l4 * 4;
      for (int nt = 0; nt < 4; nt++) {
        int s = tn * 128 + wc * 64 + nt * 16 + l15;
        for (int i = 0; i < 4; i++) {
          size_t off = ((size_t)(b * C_ + o + i)) * S_ + s;
          outp[off] = acc[mt][nt][i] + bias[o + i] + xres[off];
        }
      }
    }
  }
}

// ---------------- Flash attention: 64q/wave dual-stream, gl_lds staging -----
// (round-6 proven body) grid 512: bid = qt*32 + bh*2 + sk.
__global__ __launch_bounds__(256, 2) void k_attn(const short* __restrict__ q_sd,
                                                 const short* __restrict__ k_sd,
                                                 const short* __restrict__ v_ds,
                                                 short* __restrict__ op_base,
                                                 long op_stride,
                                                 float* __restrict__ lbuf,
                                                 int ntile) {
  int bid = blockIdx.x;
  int qt = bid >> 5;
  int bh = (bid >> 1) & 15;
  int sk = bid & 1;
  int t = threadIdx.x, w = t >> 6, lane = t & 63;
  int l31 = lane & 31, hi = lane >> 5, hi8 = hi * 8;
  int qb = qt * 256 + w * 64;

  __shared__ char smem[32768];  // 2 bufs x (K 8KB + V 8KB)

  int wb = __builtin_amdgcn_readfirstlane(w) << 10;

  int r8 = t >> 3, s8 = t & 7;
  int sw8 = (s8 ^ (r8 & 7)) * 8;
  const short* kb = k_sd + ((size_t)bh * S_ + (size_t)sk * ntile * 64) * HD_;
  const short* vbg = v_ds + (size_t)bh * HD_ * S_ + sk * ntile * 64;
  int koff0 = r8 * 64 + sw8;
  int koff1 = koff0 + 32 * 64;
  size_t voff0 = (size_t)r8 * S_ + sw8;
  size_t voff1 = voff0 + (size_t)32 * S_;

#define STAGE(bsel, ti)                                                        \
  do {                                                                         \
    const short* kt_ = kb + (size_t)(ti) * (64 * HD_);                         \
    const short* vt_ = vbg + (ti) * 64;                                        \
    char* lb_ = smem + ((bsel) << 14) + wb;                                    \
    gl_lds16(kt_ + koff0, lb_);                                                \
    gl_lds16(kt_ + koff1, lb_ + 4096);                                         \
    gl_lds16(vt_ + voff0, lb_ + 8192);                                         \
    gl_lds16(vt_ + voff1, lb_ + 12288);                                        \
  } while (0)

  const short* qpA = q_sd + ((size_t)bh * S_ + qb + l31) * HD_ + hi8;
  short8 qfA[4], qfB[4];
#pragma unroll
  for (int sl = 0; sl < 4; sl++) {
    qfA[sl] = *reinterpret_cast<const short8*>(qpA + sl * 16);
    qfB[sl] = *reinterpret_cast<const short8*>(qpA + 32 * HD_ + sl * 16);
  }

  int x7 = l31 & 7;
  int rb0 = l31 * 128;

  f32x16 OA0, OA1, OB0, OB1;
#pragma unroll
  for (int r = 0; r < 16; r++) { OA0[r] = 0.f; OA1[r] = 0.f; OB0[r] = 0.f; OB1[r] = 0.f; }
  float lA = 0.f, lB = 0.f;

  STAGE(0, 0);
  if (ntile > 1) STAGE(1, 1);
  asm volatile("s_waitcnt vmcnt(0)" ::: "memory");
  __builtin_amdgcn_s_barrier();
  asm volatile("" ::: "memory");

#define MKPA(pa, s0, s1)                                                       \
  do {                                                                         \
    unsigned c0 = pkbf(s0[0], s0[1]), c1 = pkbf(s0[2], s0[3]);                 \
    unsigned c2 = pkbf(s0[4], s0[5]), c3 = pkbf(s0[6], s0[7]);                 \
    pl32swap(c0, c2); pl32swap(c1, c3);                                        \
    uint4v u0; u0[0] = c0; u0[1] = c1; u0[2] = c2; u0[3] = c3;                 \
    pa[0] = __builtin_bit_cast(short8, u0);                                    \
    unsigned c4 = pkbf(s0[8], s0[9]), c5 = pkbf(s0[10], s0[11]);               \
    unsigned c6 = pkbf(s0[12], s0[13]), c7 = pkbf(s0[14], s0[15]);             \
    pl32swap(c4, c6); pl32swap(c5, c7);                                        \
    uint4v u1; u1[0] = c4; u1[1] = c5; u1[2] = c6; u1[3] = c7;                 \
    pa[1] = __builtin_bit_cast(short8, u1);                                    \
    unsigned d0 = pkbf(s1[0], s1[1]), d1 = pkbf(s1[2], s1[3]);                 \
    unsigned d2 = pkbf(s1[4], s1[5]), d3 = pkbf(s1[6], s1[7]);                 \
    pl32swap(d0, d2); pl32swap(d1, d3);                                        \
    uint4v u2; u2[0] = d0; u2[1] = d1; u2[2] = d2; u2[3] = d3;                 \
    pa[2] = __builtin_bit_cast(short8, u2);                                    \
    unsigned d4 = pkbf(s1[8], s1[9]), d5 = pkbf(s1[10], s1[11]);               \
    unsigned d6 = pkbf(s1[12], s1[13]), d7 = pkbf(s1[14], s1[15]);             \
    pl32swap(d4, d6); pl32swap(d5, d7);                                        \
    uint4v u3; u3[0] = d4; u3[1] = d5; u3[2] = d6; u3[3] = d7;                 \
    pa[3] = __builtin_bit_cast(short8, u3);                                    \
  } while (0)

  for (int it = 0; it < ntile; it++) {
    char* cur = smem + ((it & 1) << 14);

    f32x16 sA0, sA1, sB0, sB1;
#pragma unroll
    for (int r = 0; r < 16; r++) { sA0[r] = 0.f; sA1[r] = 0.f; sB0[r] = 0.f; sB1[r] = 0.f; }
    __builtin_amdgcn_s_setprio(1);
#pragma unroll
    for (int sl = 0; sl < 4; sl++) {
      int so = ((sl * 2 + hi) ^ x7) << 4;
      short8 kf0 = *reinterpret_cast<short8*>(cur + rb0 + so);
      short8 kf1 = *reinterpret_cast<short8*>(cur + 4096 + rb0 + so);
      sA0 = __builtin_amdgcn_mfma_f32_32x32x16_bf16(kf0, qfA[sl], sA0, 0, 0, 0);
      sB0 = __builtin_amdgcn_mfma_f32_32x32x16_bf16(kf0, qfB[sl], sB0, 0, 0, 0);
      sA1 = __builtin_amdgcn_mfma_f32_32x32x16_bf16(kf1, qfA[sl], sA1, 0, 0, 0);
      sB1 = __builtin_amdgcn_mfma_f32_32x32x16_bf16(kf1, qfB[sl], sB1, 0, 0, 0);
    }
    __builtin_amdgcn_s_setprio(0);

#pragma unroll
    for (int r = 0; r < 16; r++) sA0[r] = EXP2(sA0[r]);
#pragma unroll
    for (int r = 0; r < 16; r++) sA1[r] = EXP2(sA1[r]);
#pragma unroll
    for (int r = 0; r < 16; r++) sB0[r] = EXP2(sB0[r]);
#pragma unroll
    for (int r = 0; r < 16; r++) sB1[r] = EXP2(sB1[r]);
    {
      float a0 = 0.f, a1 = 0.f, a2 = 0.f, a3 = 0.f;
      float b0 = 0.f, b1 = 0.f, b2 = 0.f, b3 = 0.f;
#pragma unroll
      for (int r = 0; r < 16; r += 4) {
        a0 += sA0[r]; a1 += sA0[r + 1]; a2 += sA0[r + 2]; a3 += sA0[r + 3];
        a0 += sA1[r]; a1 += sA1[r + 1]; a2 += sA1[r + 2]; a3 += sA1[r + 3];
        b0 += sB0[r]; b1 += sB0[r + 1]; b2 += sB0[r + 2]; b3 += sB0[r + 3];
        b0 += sB1[r]; b1 += sB1[r + 1]; b2 += sB1[r + 2]; b3 += sB1[r + 3];
      }
      float rsA = (a0 + a1) + (a2 + a3);
      float rsB = (b0 + b1) + (b2 + b3);
      rsA += __shfl_xor(rsA, 32, 64);
      rsB += __shfl_xor(rsB, 32, 64);
      lA += rsA;
      lB += rsB;
    }

    short8 paA[4], paB[4];
    MKPA(paA, sA0, sA1);
    MKPA(paB, sB0, sB1);

    __builtin_amdgcn_s_setprio(1);
#pragma unroll
    for (int ks = 0; ks < 4; ks++) {
      int so = ((ks * 2 + hi) ^ x7) << 4;
      short8 vf0 = *reinterpret_cast<short8*>(cur + 8192 + rb0 + so);
      short8 vf1 = *reinterpret_cast<short8*>(cur + 12288 + rb0 + so);
      OA0 = __builtin_amdgcn_mfma_f32_32x32x16_bf16(vf0, paA[ks], OA0, 0, 0, 0);
      OB0 = __builtin_amdgcn_mfma_f32_32x32x16_bf16(vf0, paB[ks], OB0, 0, 0, 0);
      OA1 = __builtin_amdgcn_mfma_f32_32x32x16_bf16(vf1, paA[ks], OA1, 0, 0, 0);
      OB1 = __builtin_amdgcn_mfma_f32_32x32x16_bf16(vf1, paB[ks], OB1, 0, 0, 0);
    }
    __builtin_amdgcn_s_setprio(0);

    if (it + 1 < ntile) {
      __builtin_amdgcn_s_barrier();
      if (it + 2 < ntile) {
        STAGE(it & 1, it + 2);
        asm volatile("s_waitcnt vmcnt(4)" ::: "memory");
      } else {
        asm volatile("s_waitcnt vmcnt(0)" ::: "memory");
      }
      __builtin_amdgcn_s_barrier();
      asm volatile("" ::: "memory");
    }
  }

  short* optrA = op_base + (size_t)sk * op_stride + ((size_t)bh * S_ + qb + l31) * HD_;
  short* optrB = optrA + 32 * HD_;
#pragma unroll
  for (int qd = 0; qd < 4; qd++) {
    short4v a0, a1, b0v, b1v;
#pragma unroll
    for (int i = 0; i < 4; i++) {
      a0[i] = f2bf(OA0[qd * 4 + i]);
      a1[i] = f2bf(OA1[qd * 4 + i]);
      b0v[i] = f2bf(OB0[qd * 4 + i]);
      b1v[i] = f2bf(OB1[qd * 4 + i]);
    }
    int d0 = qd * 8 + hi * 4;
    *reinterpret_cast<short4v*>(optrA + d0) = a0;
    *reinterpret_cast<short4v*>(optrA + 32 + d0) = a1;
    *reinterpret_cast<short4v*>(optrB + d0) = b0v;
    *reinterpret_cast<short4v*>(optrB + 32 + d0) = b1v;
  }
  if (hi == 0) {
    lbuf[(size_t)(sk * 16 + bh) * S_ + qb + l31] = lA;
    lbuf[(size_t)(sk * 16 + bh) * S_ + qb + 32 + l31] = lB;
  }
#undef STAGE
#undef MKPA
}

extern "C" void kernel_launch(void* const* d_in, const int* in_sizes, int n_in,
                              void* d_out, int out_size, void* d_ws, size_t ws_size,
                              hipStream_t stream) {
  const float* x      = (const float*)d_in[0];
  const float* gn_w   = (const float*)d_in[1];
  const float* gn_b   = (const float*)d_in[2];
  const float* qkv_w  = (const float*)d_in[3];
  const float* qkv_b  = (const float*)d_in[4];
  const float* proj_w = (const float*)d_in[5];
  const float* proj_b = (const float*)d_in[6];
  char* ws = (char*)d_ws;
  float* part  = (float*)(ws + 2048);      // 512 floats
  short* wqkv  = (short*)(ws + 4096);
  short* wproj = (short*)(ws + 397312);
  short* q_sd  = (short*)(ws + 8916992);
  short* k_sd  = (short*)(ws + 17305600);
  short* v_ds  = (short*)(ws + 25694208);
  short* op_base = (short*)(ws + 528384);  // old xnt slot, now pure O-partial scratch
  long op_stride = (42471424 - 528384) / 2;  // op1 at ws+42471424
  float* lbuf  = (float*)(ws + 50860032);  // [2][16][4096] f32
  float* outp  = (float*)d_out;

  k_pre<<<256, 256, 0, stream>>>(x, qkv_w, proj_w, part, wqkv, wproj);
  k_gemm<0, 0><<<dim3(32, 6, 4), 256, 0, stream>>>(wqkv, x, gn_w, gn_b, part, nullptr,
                                                   qkv_b, nullptr, q_sd, k_sd, v_ds,
                                                   0, nullptr, nullptr);
  k_attn<<<512, 256, 0, stream>>>(q_sd, k_sd, v_ds, op_base, op_stride, lbuf, 32);
  k_gemm<1, 2><<<dim3(32, 2, 4), 256, 0, stream>>>(wproj, nullptr, nullptr, nullptr, nullptr,
                                                   op_base, proj_b, x, nullptr, nullptr, nullptr,
                                                   op_stride, lbuf, outp);
}

// Round 16
// 125.394 us; speedup vs baseline: 1.0479x; 1.0479x over previous
//
#include <hip/hip_runtime.h>
#include <hip/hip_bf16.h>

#define B_ 4
#define C_ 256
#define S_ 4096
#define NH_ 4
#define HD_ 64
#define LOG2E 1.4426950408889634f
#define QSC 0.18033688011112042f  // 0.125 * log2(e), folded into W_q

typedef __attribute__((ext_vector_type(8))) short short8;
typedef __attribute__((ext_vector_type(4))) short short4v;
typedef __attribute__((ext_vector_type(4))) float f32x4;
typedef __attribute__((ext_vector_type(16))) float f32x16;
typedef __attribute__((ext_vector_type(4))) unsigned uint4v;

static __device__ __forceinline__ short f2bf(float f) {
  unsigned u = __builtin_bit_cast(unsigned, f);
  u += 0x7fffu + ((u >> 16) & 1u);
  return (short)(u >> 16);
}
static __device__ __forceinline__ float bf2f(short h) {
  unsigned u = ((unsigned)(unsigned short)h) << 16;
  return __builtin_bit_cast(float, u);
}

#if __has_builtin(__builtin_amdgcn_exp2f)
#define EXP2(x) __builtin_amdgcn_exp2f(x)
#else
#define EXP2(x) exp2f(x)
#endif

static __device__ __forceinline__ unsigned pkbf(float a, float b) {
  unsigned r;
  asm("v_cvt_pk_bf16_f32 %0, %1, %2" : "=v"(r) : "v"(a), "v"(b));
  return r;
}
static __device__ __forceinline__ void pl32swap(unsigned& a, unsigned& b) {
  asm volatile("v_permlane32_swap_b32 %0, %1" : "+v"(a), "+v"(b));
}
// async global->LDS, 16B per lane; lds dest = wave-uniform base + lane*16
static __device__ __forceinline__ void gl_lds16(const short* g, char* l) {
  __builtin_amdgcn_global_load_lds(
      (const __attribute__((address_space(1))) void*)g,
      (__attribute__((address_space(3))) void*)l, 16, 0, 0);
}

// ---------------- k_pre: GroupNorm partial sums + weight convert ------------
__global__ __launch_bounds__(256) void k_pre(const float* __restrict__ x,
                                             const float* __restrict__ wq,
                                             const float* __restrict__ wp,
                                             float* __restrict__ part,
                                             short* __restrict__ oq,
                                             short* __restrict__ op) {
  int t = threadIdx.x;
  const float* p = x + (size_t)blockIdx.x * 16384;
  float s = 0.f, ss = 0.f;
  const float4* p4 = reinterpret_cast<const float4*>(p);
  for (int i = t; i < 4096; i += 256) {
    float4 v = p4[i];
    s += v.x + v.y + v.z + v.w;
    ss += v.x * v.x + v.y * v.y + v.z * v.z + v.w * v.w;
  }
  for (int m = 1; m < 64; m <<= 1) {
    s += __shfl_xor(s, m, 64);
    ss += __shfl_xor(ss, m, 64);
  }
  __shared__ float rs[4], rss[4];
  int w = t >> 6;
  if ((t & 63) == 0) { rs[w] = s; rss[w] = ss; }
  {
    int i = (blockIdx.x * 256 + t) * 4;
    const int n1 = 768 * 256;
    float sc = 1.f;
    const float* src;
    short* dst;
    if (i < n1) {
      src = wq + i; dst = oq + i;
      if (i < 256 * 256) sc = QSC;
    } else {
      src = wp + (i - n1); dst = op + (i - n1);
    }
    float4 v = *reinterpret_cast<const float4*>(src);
    short4v o;
    o[0] = f2bf(v.x * sc); o[1] = f2bf(v.y * sc);
    o[2] = f2bf(v.z * sc); o[3] = f2bf(v.w * sc);
    *reinterpret_cast<short4v*>(dst) = o;
  }
  __syncthreads();
  if (t == 0) {
    part[2 * blockIdx.x] = rs[0] + rs[1] + rs[2] + rs[3];
    part[2 * blockIdx.x + 1] = rss[0] + rss[1] + rss[2] + rss[3];
  }
}

// ---------------- GN apply + transpose (stats finalized in-block) -----------
__global__ __launch_bounds__(256) void k_gn_apply(const float* __restrict__ x,
                                                  const float* __restrict__ gw,
                                                  const float* __restrict__ gb,
                                                  const float* __restrict__ part,
                                                  short* __restrict__ xnt) {
  int st = blockIdx.x;
  int ct = blockIdx.y;
  int b = blockIdx.z;
  int t = threadIdx.x;
  __shared__ short T[64 * 72];
  __shared__ float smu[2], sri[2];
  int c0 = ct * 64, s0 = st * 64;
  if (t < 2) {
    int g = (c0 >> 5) + t;
    int base = b * 64 + g * 8;
    float s = 0.f, ss = 0.f;
    for (int j = 0; j < 8; j++) {
      s += part[2 * (base + j)];
      ss += part[2 * (base + j) + 1];
    }
    float inv = 1.f / (32.f * S_);
    float mu = s * inv;
    float var = ss * inv - mu * mu;
    smu[t] = mu;
    sri[t] = rsqrtf(var + 1e-5f);
  }
  __syncthreads();
  int r4 = t >> 4;
  int f4 = t & 15;
  for (int p = 0; p < 4; p++) {
    int r = p * 16 + r4;
    int c = c0 + r;
    int gl = r >> 5;
    float mu = smu[gl];
    float ri = sri[gl];
    float A = gw[c] * ri;
    float Bb = gb[c] - mu * A;
    float4 v = *reinterpret_cast<const float4*>(x + ((size_t)(b * C_ + c)) * S_ + s0 + f4 * 4);
    int sb = f4 * 4;
    T[(sb + 0) * 72 + r] = f2bf(v.x * A + Bb);
    T[(sb + 1) * 72 + r] = f2bf(v.y * A + Bb);
    T[(sb + 2) * 72 + r] = f2bf(v.z * A + Bb);
    T[(sb + 3) * 72 + r] = f2bf(v.w * A + Bb);
  }
  __syncthreads();
  for (int it = 0; it < 2; it++) {
    int cch = t + it * 256;
    int sl = cch >> 3, c8 = cch & 7;
    short8 v = *reinterpret_cast<short8*>(&T[sl * 72 + c8 * 8]);
    *reinterpret_cast<short8*>(xnt + ((size_t)(b * S_ + s0 + sl)) * C_ + c0 + c8 * 8) = v;
  }
}

// ---------------- GEMM (TN, bf16 MFMA) ----------------
// MODE 0: qkv — A and B both gl_lds-staged, double-buffered, 1 barrier/step.
// MODE 1: proj — A gl_lds single-buffer; B computed as (sum op_i)/(sum l_i).
template <int MODE, int NSP>
__global__ __launch_bounds__(256) void k_gemm(const short* __restrict__ Wbf,
                                              const short* __restrict__ Xt,
                                              const float* __restrict__ bias,
                                              const float* __restrict__ xres,
                                              short* __restrict__ q_sd,
                                              short* __restrict__ k_sd,
                                              short* __restrict__ v_ds,
                                              long op_stride,
                                              const float* __restrict__ lbufg,
                                              float* __restrict__ outp) {
  int tn = blockIdx.x;
  int tm = blockIdx.y;
  int b = blockIdx.z;
  int t = threadIdx.x;
  __shared__ short lds[4 * 64 * 72];  // 36864 B; staging + epilogue reuse
  char* glds = (char*)lds;
  short* Blp = lds + 4096;  // MODE 1 padded B base (shorts), [128][40]
  int w = t >> 6, lane = t & 63;
  int wr = w >> 1, wc = w & 1;
  int l15 = lane & 15, l4 = lane >> 4;
  int wbg = __builtin_amdgcn_readfirstlane(w) << 10;

  f32x4 acc[4][4];
  for (int m = 0; m < 4; m++)
    for (int n = 0; n < 4; n++)
      for (int j = 0; j < 4; j++) acc[m][n][j] = 0.f;

  const short* Arow = Wbf + (size_t)(tm * 128) * 256;
  const short* Brow = Xt + ((size_t)b * S_ + tn * 128) * 256;

  // staging source offsets (pre-swizzled): slot s -> r=s>>2, c=s&3,
  // global chunk = c ^ ((r>>1)&3)
  int r0 = t >> 2, c40 = t & 3;
  int sw0 = (c40 ^ ((r0 >> 1) & 3)) * 8;       // shorts
  int r1 = (t + 256) >> 2;
  int sw1 = (c40 ^ ((r1 >> 1) & 3)) * 8;

  if (MODE == 0) {
    // prologue: stage step 0 -> buf0
    gl_lds16(Arow + (size_t)r0 * 256 + sw0, glds + wbg);
    gl_lds16(Arow + (size_t)r1 * 256 + sw1, glds + 4096 + wbg);
    gl_lds16(Brow + (size_t)r0 * 256 + sw0, glds + 8192 + wbg);
    gl_lds16(Brow + (size_t)r1 * 256 + sw1, glds + 12288 + wbg);
    asm volatile("s_waitcnt vmcnt(0)" ::: "memory");
    __builtin_amdgcn_s_barrier();
    asm volatile("" ::: "memory");
    for (int step = 0; step < 8; step++) {
      char* cb = glds + ((step & 1) << 14);
      if (step + 1 < 8) {  // stage next step into the other buffer (top-issue)
        char* nb = glds + (((step + 1) & 1) << 14);
        int kk = (step + 1) * 32;
        gl_lds16(Arow + (size_t)r0 * 256 + kk + sw0, nb + wbg);
        gl_lds16(Arow + (size_t)r1 * 256 + kk + sw1, nb + 4096 + wbg);
        gl_lds16(Brow + (size_t)r0 * 256 + kk + sw0, nb + 8192 + wbg);
        gl_lds16(Brow + (size_t)r1 * 256 + kk + sw1, nb + 12288 + wbg);
      }
      short8 af[4], bf[4];
      for (int mt = 0; mt < 4; mt++) {
        int row = wr * 64 + mt * 16 + l15;
        af[mt] = *reinterpret_cast<short8*>(cb + row * 64 + ((l4 ^ ((row >> 1) & 3)) << 4));
      }
      for (int nt = 0; nt < 4; nt++) {
        int row = wc * 64 + nt * 16 + l15;
        bf[nt] = *reinterpret_cast<short8*>(cb + 8192 + row * 64 + ((l4 ^ ((row >> 1) & 3)) << 4));
      }
      for (int mt = 0; mt < 4; mt++)
        for (int nt = 0; nt < 4; nt++)
          acc[mt][nt] =
              __builtin_amdgcn_mfma_f32_16x16x32_bf16(af[mt], bf[nt], acc[mt][nt], 0, 0, 0);
      if (step + 1 < 8) {
        asm volatile("s_waitcnt vmcnt(0)" ::: "memory");  // next tile landed
        __builtin_amdgcn_s_barrier();
        asm volatile("" ::: "memory");
      }
    }
  } else {
    for (int kk = 0; kk < 256; kk += 32) {
      __syncthreads();  // previous tile fully consumed
      gl_lds16(Arow + (size_t)r0 * 256 + kk + sw0, glds + wbg);
      gl_lds16(Arow + (size_t)r1 * 256 + kk + sw1, glds + 4096 + wbg);
      for (int i = 0; i < 2; i++) {
        int cch = t + i * 256;
        int r = cch >> 2, c4 = cch & 3;
        int c = kk + c4 * 8;
        int bh2 = b * 4 + (c >> 6);
        int d = c & 63;
        int s_glob = tn * 128 + r;
        size_t ro = ((size_t)bh2 * S_ + s_glob) * HD_ + d;
        float a8[8] = {0.f, 0.f, 0.f, 0.f, 0.f, 0.f, 0.f, 0.f};
        float l = 0.f;
#pragma unroll
        for (int i2 = 0; i2 < NSP; i2++) {
          short8 pv = *reinterpret_cast<const short8*>(Xt + (size_t)i2 * op_stride + ro);
#pragma unroll
          for (int j = 0; j < 8; j++) a8[j] += bf2f(pv[j]);
          l += lbufg[(size_t)(i2 * 16 + bh2) * S_ + s_glob];
        }
        float inv = 1.f / l;
        short8 vbv;
#pragma unroll
        for (int j = 0; j < 8; j++) vbv[j] = f2bf(a8[j] * inv);
        *reinterpret_cast<short8*>(&Blp[r * 40 + c4 * 8]) = vbv;
      }
      asm volatile("s_waitcnt vmcnt(0)" ::: "memory");
      __syncthreads();

      short8 af[4], bf[4];
      for (int mt = 0; mt < 4; mt++) {
        int row = wr * 64 + mt * 16 + l15;
        af[mt] = *reinterpret_cast<short8*>(glds + row * 64 + ((l4 ^ ((row >> 1) & 3)) << 4));
      }
      for (int nt = 0; nt < 4; nt++) {
        int row = wc * 64 + nt * 16 + l15;
        bf[nt] = *reinterpret_cast<short8*>(&Blp[row * 40 + l4 * 8]);
      }
      for (int mt = 0; mt < 4; mt++)
        for (int nt = 0; nt < 4; nt++)
          acc[mt][nt] =
              __builtin_amdgcn_mfma_f32_16x16x32_bf16(af[mt], bf[nt], acc[mt][nt], 0, 0, 0);
    }
  }
  __syncthreads();

  if (MODE == 0) {
    int o_base = tm * 128 + wr * 64;
    int tt = o_base >> 8;
    int h = (o_base >> 6) & 3;
    int s_base = tn * 128 + wc * 64;
    int bh = b * NH_ + h;
    if (tt == 2) {
      for (int mt = 0; mt < 4; mt++)
        for (int nt = 0; nt < 4; nt++)
          for (int i = 0; i < 4; i++) {
            int o = o_base + mt * 16 + l4 * 4 + i;
            int dd = o & 63;
            int s = s_base + nt * 16 + l15;
            float val = acc[mt][nt][i] + bias[o];
            v_ds[((size_t)bh * HD_ + dd) * S_ + s] = f2bf(val);
          }
    } else {
      float bsc = (tt == 0) ? QSC : 1.f;  // q bias scaled like W_q
      short* T = lds + w * (64 * 72);
      for (int mt = 0; mt < 4; mt++)
        for (int nt = 0; nt < 4; nt++)
          for (int i = 0; i < 4; i++) {
            int o = o_base + mt * 16 + l4 * 4 + i;
            int dd = mt * 16 + l4 * 4 + i;
            int sl = nt * 16 + l15;
            float val = acc[mt][nt][i] + bias[o] * bsc;
            T[sl * 72 + dd] = f2bf(val);
          }
      short* dst = (tt == 0) ? q_sd : k_sd;
      for (int it = 0; it < 8; it++) {
        int cch = lane + it * 64;
        int sl = cch >> 3, c8 = cch & 7;
        short8 v = *reinterpret_cast<short8*>(&T[sl * 72 + c8 * 8]);
        *reinterpret_cast<short8*>(dst + ((size_t)bh * S_ + s_base + sl) * HD_ + c8 * 8) = v;
      }
    }
  } else {
    for (int mt = 0; mt < 4; mt++) {
      int o = tm * 128 + wr * 64 + mt * 16 + l4 * 4;
      for (int nt = 0; nt < 4; nt++) {
        int s = tn * 128 + wc * 64 + nt * 16 + l15;
        for (int i = 0; i < 4; i++) {
          size_t off = ((size_t)(b * C_ + o + i)) * S_ + s;
          outp[off] = acc[mt][nt][i] + bias[o + i] + xres[off];
        }
      }
    }
  }
}

// ---------------- Flash attention: 64q/wave dual-stream, triple-buffered ----
// grid 512: bid = qt*32 + bh*2 + sk. 3 LDS buffers -> ONE barrier per tile;
// tile it+2's staging target was consumed at it-1 (all waves past that
// barrier), so stage-at-top needs no "done reading" barrier.
__global__ __launch_bounds__(256, 2) void k_attn(const short* __restrict__ q_sd,
                                                 const short* __restrict__ k_sd,
                                                 const short* __restrict__ v_ds,
                                                 short* __restrict__ op_base,
                                                 long op_stride,
                                                 float* __restrict__ lbuf,
                                                 int ntile) {
  int bid = blockIdx.x;
  int qt = bid >> 5;
  int bh = (bid >> 1) & 15;
  int sk = bid & 1;
  int t = threadIdx.x, w = t >> 6, lane = t & 63;
  int l31 = lane & 31, hi = lane >> 5, hi8 = hi * 8;
  int qb = qt * 256 + w * 64;

  __shared__ char smem[49152];  // 3 bufs x (K 8KB + V 8KB)

  int wb = __builtin_amdgcn_readfirstlane(w) << 10;

  int r8 = t >> 3, s8 = t & 7;
  int sw8 = (s8 ^ (r8 & 7)) * 8;
  const short* kb = k_sd + ((size_t)bh * S_ + (size_t)sk * ntile * 64) * HD_;
  const short* vbg = v_ds + (size_t)bh * HD_ * S_ + sk * ntile * 64;
  int koff0 = r8 * 64 + sw8;
  int koff1 = koff0 + 32 * 64;
  size_t voff0 = (size_t)r8 * S_ + sw8;
  size_t voff1 = voff0 + (size_t)32 * S_;

#define STAGE(bsel, ti)                                                        \
  do {                                                                         \
    const short* kt_ = kb + (size_t)(ti) * (64 * HD_);                         \
    const short* vt_ = vbg + (ti) * 64;                                        \
    char* lb_ = smem + ((bsel) << 14) + wb;                                    \
    gl_lds16(kt_ + koff0, lb_);                                                \
    gl_lds16(kt_ + koff1, lb_ + 4096);                                         \
    gl_lds16(vt_ + voff0, lb_ + 8192);                                         \
    gl_lds16(vt_ + voff1, lb_ + 12288);                                        \
  } while (0)

  const short* qpA = q_sd + ((size_t)bh * S_ + qb + l31) * HD_ + hi8;
  short8 qfA[4], qfB[4];
#pragma unroll
  for (int sl = 0; sl < 4; sl++) {
    qfA[sl] = *reinterpret_cast<const short8*>(qpA + sl * 16);
    qfB[sl] = *reinterpret_cast<const short8*>(qpA + 32 * HD_ + sl * 16);
  }

  int x7 = l31 & 7;
  int rb0 = l31 * 128;

  f32x16 OA0, OA1, OB0, OB1;
#pragma unroll
  for (int r = 0; r < 16; r++) { OA0[r] = 0.f; OA1[r] = 0.f; OB0[r] = 0.f; OB1[r] = 0.f; }
  float lA = 0.f, lB = 0.f;

  // prologue: stage tiles 0,1 into bufs 0,1; wait tile 0 only (vmcnt(4))
  STAGE(0, 0);
  if (ntile > 1) STAGE(1, 1);
  asm volatile("s_waitcnt vmcnt(4)" ::: "memory");
  __builtin_amdgcn_s_barrier();
  asm volatile("" ::: "memory");

#define MKPA(pa, s0, s1)                                                       \
  do {                                                                         \
    unsigned c0 = pkbf(s0[0], s0[1]), c1 = pkbf(s0[2], s0[3]);                 \
    unsigned c2 = pkbf(s0[4], s0[5]), c3 = pkbf(s0[6], s0[7]);                 \
    pl32swap(c0, c2); pl32swap(c1, c3);                                        \
    uint4v u0; u0[0] = c0; u0[1] = c1; u0[2] = c2; u0[3] = c3;                 \
    pa[0] = __builtin_bit_cast(short8, u0);                                    \
    unsigned c4 = pkbf(s0[8], s0[9]), c5 = pkbf(s0[10], s0[11]);               \
    unsigned c6 = pkbf(s0[12], s0[13]), c7 = pkbf(s0[14], s0[15]);             \
    pl32swap(c4, c6); pl32swap(c5, c7);                                        \
    uint4v u1; u1[0] = c4; u1[1] = c5; u1[2] = c6; u1[3] = c7;                 \
    pa[1] = __builtin_bit_cast(short8, u1);                                    \
    unsigned d0 = pkbf(s1[0], s1[1]), d1 = pkbf(s1[2], s1[3]);                 \
    unsigned d2 = pkbf(s1[4], s1[5]), d3 = pkbf(s1[6], s1[7]);                 \
    pl32swap(d0, d2); pl32swap(d1, d3);                                        \
    uint4v u2; u2[0] = d0; u2[1] = d1; u2[2] = d2; u2[3] = d3;                 \
    pa[2] = __builtin_bit_cast(short8, u2);                                    \
    unsigned d4 = pkbf(s1[8], s1[9]), d5 = pkbf(s1[10], s1[11]);               \
    unsigned d6 = pkbf(s1[12], s1[13]), d7 = pkbf(s1[14], s1[15]);             \
    pl32swap(d4, d6); pl32swap(d5, d7);                                        \
    uint4v u3; u3[0] = d4; u3[1] = d5; u3[2] = d6; u3[3] = d7;                 \
    pa[3] = __builtin_bit_cast(short8, u3);                                    \
  } while (0)

  int cs = 0;  // current buffer selector (rotates 0,1,2)
  for (int it = 0; it < ntile; it++) {
    char* cur = smem + (cs << 14);
    int ns = (cs == 2) ? 0 : cs + 1;
    int ps = (cs == 0) ? 2 : cs - 1;  // (cs+2)%3: consumed at it-1, safe target
    if (it + 2 < ntile) STAGE(ps, it + 2);

    f32x16 sA0, sA1, sB0, sB1;
#pragma unroll
    for (int r = 0; r < 16; r++) { sA0[r] = 0.f; sA1[r] = 0.f; sB0[r] = 0.f; sB1[r] = 0.f; }
    __builtin_amdgcn_s_setprio(1);
#pragma unroll
    for (int sl = 0; sl < 4; sl++) {
      int so = ((sl * 2 + hi) ^ x7) << 4;
      short8 kf0 = *reinterpret_cast<short8*>(cur + rb0 + so);
      short8 kf1 = *reinterpret_cast<short8*>(cur + 4096 + rb0 + so);
      sA0 = __builtin_amdgcn_mfma_f32_32x32x16_bf16(kf0, qfA[sl], sA0, 0, 0, 0);
      sB0 = __builtin_amdgcn_mfma_f32_32x32x16_bf16(kf0, qfB[sl], sB0, 0, 0, 0);
      sA1 = __builtin_amdgcn_mfma_f32_32x32x16_bf16(kf1, qfA[sl], sA1, 0, 0, 0);
      sB1 = __builtin_amdgcn_mfma_f32_32x32x16_bf16(kf1, qfB[sl], sB1, 0, 0, 0);
    }
    __builtin_amdgcn_s_setprio(0);

#pragma unroll
    for (int r = 0; r < 16; r++) sA0[r] = EXP2(sA0[r]);
#pragma unroll
    for (int r = 0; r < 16; r++) sA1[r] = EXP2(sA1[r]);
#pragma unroll
    for (int r = 0; r < 16; r++) sB0[r] = EXP2(sB0[r]);
#pragma unroll
    for (int r = 0; r < 16; r++) sB1[r] = EXP2(sB1[r]);
    {
      float a0 = 0.f, a1 = 0.f, a2 = 0.f, a3 = 0.f;
      float b0 = 0.f, b1 = 0.f, b2 = 0.f, b3 = 0.f;
#pragma unroll
      for (int r = 0; r < 16; r += 4) {
        a0 += sA0[r]; a1 += sA0[r + 1]; a2 += sA0[r + 2]; a3 += sA0[r + 3];
        a0 += sA1[r]; a1 += sA1[r + 1]; a2 += sA1[r + 2]; a3 += sA1[r + 3];
        b0 += sB0[r]; b1 += sB0[r + 1]; b2 += sB0[r + 2]; b3 += sB0[r + 3];
        b0 += sB1[r]; b1 += sB1[r + 1]; b2 += sB1[r + 2]; b3 += sB1[r + 3];
      }
      float rsA = (a0 + a1) + (a2 + a3);
      float rsB = (b0 + b1) + (b2 + b3);
      rsA += __shfl_xor(rsA, 32, 64);
      rsB += __shfl_xor(rsB, 32, 64);
      lA += rsA;
      lB += rsB;
    }

    short8 paA[4], paB[4];
    MKPA(paA, sA0, sA1);
    MKPA(paB, sB0, sB1);

    __builtin_amdgcn_s_setprio(1);
#pragma unroll
    for (int ks = 0; ks < 4; ks++) {
      int so = ((ks * 2 + hi) ^ x7) << 4;
      short8 vf0 = *reinterpret_cast<short8*>(cur + 8192 + rb0 + so);
      short8 vf1 = *reinterpret_cast<short8*>(cur + 12288 + rb0 + so);
      OA0 = __builtin_amdgcn_mfma_f32_32x32x16_bf16(vf0, paA[ks], OA0, 0, 0, 0);
      OB0 = __builtin_amdgcn_mfma_f32_32x32x16_bf16(vf0, paB[ks], OB0, 0, 0, 0);
      OA1 = __builtin_amdgcn_mfma_f32_32x32x16_bf16(vf1, paA[ks], OA1, 0, 0, 0);
      OB1 = __builtin_amdgcn_mfma_f32_32x32x16_bf16(vf1, paB[ks], OB1, 0, 0, 0);
    }
    __builtin_amdgcn_s_setprio(0);

    // single barrier per tile: own stage for it+2 in flight (vmcnt 4),
    // it+1's loads complete (each wave), then all waves rendezvous.
    if (it + 1 < ntile) {
      if (it + 2 < ntile)
        asm volatile("s_waitcnt vmcnt(4)" ::: "memory");
      else
        asm volatile("s_waitcnt vmcnt(0)" ::: "memory");
      __builtin_amdgcn_s_barrier();
      asm volatile("" ::: "memory");
    }
    cs = ns;
  }

  short* optrA = op_base + (size_t)sk * op_stride + ((size_t)bh * S_ + qb + l31) * HD_;
  short* optrB = optrA + 32 * HD_;
#pragma unroll
  for (int qd = 0; qd < 4; qd++) {
    short4v a0, a1, b0v, b1v;
#pragma unroll
    for (int i = 0; i < 4; i++) {
      a0[i] = f2bf(OA0[qd * 4 + i]);
      a1[i] = f2bf(OA1[qd * 4 + i]);
      b0v[i] = f2bf(OB0[qd * 4 + i]);
      b1v[i] = f2bf(OB1[qd * 4 + i]);
    }
    int d0 = qd * 8 + hi * 4;
    *reinterpret_cast<short4v*>(optrA + d0) = a0;
    *reinterpret_cast<short4v*>(optrA + 32 + d0) = a1;
    *reinterpret_cast<short4v*>(optrB + d0) = b0v;
    *reinterpret_cast<short4v*>(optrB + 32 + d0) = b1v;
  }
  if (hi == 0) {
    lbuf[(size_t)(sk * 16 + bh) * S_ + qb + l31] = lA;
    lbuf[(size_t)(sk * 16 + bh) * S_ + qb + 32 + l31] = lB;
  }
#undef STAGE
#undef MKPA
}

extern "C" void kernel_launch(void* const* d_in, const int* in_sizes, int n_in,
                              void* d_out, int out_size, void* d_ws, size_t ws_size,
                              hipStream_t stream) {
  const float* x      = (const float*)d_in[0];
  const float* gn_w   = (const float*)d_in[1];
  const float* gn_b   = (const float*)d_in[2];
  const float* qkv_w  = (const float*)d_in[3];
  const float* qkv_b  = (const float*)d_in[4];
  const float* proj_w = (const float*)d_in[5];
  const float* proj_b = (const float*)d_in[6];
  char* ws = (char*)d_ws;
  float* part  = (float*)(ws + 2048);      // 512 floats
  short* wqkv  = (short*)(ws + 4096);
  short* wproj = (short*)(ws + 397312);
  short* xnt   = (short*)(ws + 528384);    // [4][4096][256] bf16 (reused as op0)
  short* q_sd  = (short*)(ws + 8916992);
  short* k_sd  = (short*)(ws + 17305600);
  short* v_ds  = (short*)(ws + 25694208);
  short* op_base = xnt;                    // xnt dead after gemm<0>
  long op_stride = (42471424 - 528384) / 2;  // op1 at ws+42471424
  float* lbuf  = (float*)(ws + 50860032);  // [2][16][4096] f32
  float* outp  = (float*)d_out;

  k_pre<<<256, 256, 0, stream>>>(x, qkv_w, proj_w, part, wqkv, wproj);
  k_gn_apply<<<dim3(64, 4, 4), 256, 0, stream>>>(x, gn_w, gn_b, part, xnt);
  k_gemm<0, 0><<<dim3(32, 6, 4), 256, 0, stream>>>(wqkv, xnt, qkv_b, nullptr, q_sd, k_sd, v_ds,
                                                   0, nullptr, nullptr);
  k_attn<<<512, 256, 0, stream>>>(q_sd, k_sd, v_ds, op_base, op_stride, lbuf, 32);
  k_gemm<1, 2><<<dim3(32, 2, 4), 256, 0, stream>>>(wproj, op_base, proj_b, x, nullptr, nullptr,
                                                   nullptr, op_stride, lbuf, outp);
}

// Round 17
// 125.209 us; speedup vs baseline: 1.0495x; 1.0015x over previous
//
#include <hip/hip_runtime.h>
#include <hip/hip_bf16.h>

#define B_ 4
#define C_ 256
#define S_ 4096
#define NH_ 4
#define HD_ 64
#define LOG2E 1.4426950408889634f
#define QSC 0.18033688011112042f  // 0.125 * log2(e), folded into W_q

typedef __attribute__((ext_vector_type(8))) short short8;
typedef __attribute__((ext_vector_type(4))) short short4v;
typedef __attribute__((ext_vector_type(4))) float f32x4;
typedef __attribute__((ext_vector_type(16))) float f32x16;
typedef __attribute__((ext_vector_type(4))) unsigned uint4v;

static __device__ __forceinline__ short f2bf(float f) {
  unsigned u = __builtin_bit_cast(unsigned, f);
  u += 0x7fffu + ((u >> 16) & 1u);
  return (short)(u >> 16);
}
static __device__ __forceinline__ float bf2f(short h) {
  unsigned u = ((unsigned)(unsigned short)h) << 16;
  return __builtin_bit_cast(float, u);
}

#if __has_builtin(__builtin_amdgcn_exp2f)
#define EXP2(x) __builtin_amdgcn_exp2f(x)
#else
#define EXP2(x) exp2f(x)
#endif

static __device__ __forceinline__ unsigned pkbf(float a, float b) {
  unsigned r;
  asm("v_cvt_pk_bf16_f32 %0, %1, %2" : "=v"(r) : "v"(a), "v"(b));
  return r;
}
static __device__ __forceinline__ void pl32swap(unsigned& a, unsigned& b) {
  asm volatile("v_permlane32_swap_b32 %0, %1" : "+v"(a), "+v"(b));
}
// async global->LDS, 16B per lane; lds dest = wave-uniform base + lane*16
static __device__ __forceinline__ void gl_lds16(const short* g, char* l) {
  __builtin_amdgcn_global_load_lds(
      (const __attribute__((address_space(1))) void*)g,
      (__attribute__((address_space(3))) void*)l, 16, 0, 0);
}

// ---------------- k_pre: GroupNorm partial sums + weight convert ------------
__global__ __launch_bounds__(256) void k_pre(const float* __restrict__ x,
                                             const float* __restrict__ wq,
                                             const float* __restrict__ wp,
                                             float* __restrict__ part,
                                             short* __restrict__ oq,
                                             short* __restrict__ op) {
  int t = threadIdx.x;
  const float* p = x + (size_t)blockIdx.x * 16384;
  float s = 0.f, ss = 0.f;
  const float4* p4 = reinterpret_cast<const float4*>(p);
  for (int i = t; i < 4096; i += 256) {
    float4 v = p4[i];
    s += v.x + v.y + v.z + v.w;
    ss += v.x * v.x + v.y * v.y + v.z * v.z + v.w * v.w;
  }
  for (int m = 1; m < 64; m <<= 1) {
    s += __shfl_xor(s, m, 64);
    ss += __shfl_xor(ss, m, 64);
  }
  __shared__ float rs[4], rss[4];
  int w = t >> 6;
  if ((t & 63) == 0) { rs[w] = s; rss[w] = ss; }
  {
    int i = (blockIdx.x * 256 + t) * 4;
    const int n1 = 768 * 256;
    float sc = 1.f;
    const float* src;
    short* dst;
    if (i < n1) {
      src = wq + i; dst = oq + i;
      if (i < 256 * 256) sc = QSC;
    } else {
      src = wp + (i - n1); dst = op + (i - n1);
    }
    float4 v = *reinterpret_cast<const float4*>(src);
    short4v o;
    o[0] = f2bf(v.x * sc); o[1] = f2bf(v.y * sc);
    o[2] = f2bf(v.z * sc); o[3] = f2bf(v.w * sc);
    *reinterpret_cast<short4v*>(dst) = o;
  }
  __syncthreads();
  if (t == 0) {
    part[2 * blockIdx.x] = rs[0] + rs[1] + rs[2] + rs[3];
    part[2 * blockIdx.x + 1] = rss[0] + rss[1] + rss[2] + rss[3];
  }
}

// ---------------- GN apply + transpose (stats finalized in-block) -----------
__global__ __launch_bounds__(256) void k_gn_apply(const float* __restrict__ x,
                                                  const float* __restrict__ gw,
                                                  const float* __restrict__ gb,
                                                  const float* __restrict__ part,
                                                  short* __restrict__ xnt) {
  int st = blockIdx.x;
  int ct = blockIdx.y;
  int b = blockIdx.z;
  int t = threadIdx.x;
  __shared__ short T[64 * 72];
  __shared__ float smu[2], sri[2];
  int c0 = ct * 64, s0 = st * 64;
  if (t < 2) {
    int g = (c0 >> 5) + t;
    int base = b * 64 + g * 8;
    float s = 0.f, ss = 0.f;
    for (int j = 0; j < 8; j++) {
      s += part[2 * (base + j)];
      ss += part[2 * (base + j) + 1];
    }
    float inv = 1.f / (32.f * S_);
    float mu = s * inv;
    float var = ss * inv - mu * mu;
    smu[t] = mu;
    sri[t] = rsqrtf(var + 1e-5f);
  }
  __syncthreads();
  int r4 = t >> 4;
  int f4 = t & 15;
  for (int p = 0; p < 4; p++) {
    int r = p * 16 + r4;
    int c = c0 + r;
    int gl = r >> 5;
    float mu = smu[gl];
    float ri = sri[gl];
    float A = gw[c] * ri;
    float Bb = gb[c] - mu * A;
    float4 v = *reinterpret_cast<const float4*>(x + ((size_t)(b * C_ + c)) * S_ + s0 + f4 * 4);
    int sb = f4 * 4;
    T[(sb + 0) * 72 + r] = f2bf(v.x * A + Bb);
    T[(sb + 1) * 72 + r] = f2bf(v.y * A + Bb);
    T[(sb + 2) * 72 + r] = f2bf(v.z * A + Bb);
    T[(sb + 3) * 72 + r] = f2bf(v.w * A + Bb);
  }
  __syncthreads();
  for (int it = 0; it < 2; it++) {
    int cch = t + it * 256;
    int sl = cch >> 3, c8 = cch & 7;
    short8 v = *reinterpret_cast<short8*>(&T[sl * 72 + c8 * 8]);
    *reinterpret_cast<short8*>(xnt + ((size_t)(b * S_ + s0 + sl)) * C_ + c0 + c8 * 8) = v;
  }
}

// ---------------- GEMM (TN, bf16 MFMA) ----------------
// MODE 0: qkv — A and B both gl_lds-staged, double-buffered, 1 barrier/step.
// MODE 1: proj — A gl_lds single-buffer; B computed as (sum op_i)/(sum l_i).
template <int MODE, int NSP>
__global__ __launch_bounds__(256) void k_gemm(const short* __restrict__ Wbf,
                                              const short* __restrict__ Xt,
                                              const float* __restrict__ bias,
                                              const float* __restrict__ xres,
                                              short* __restrict__ q_sd,
                                              short* __restrict__ k_sd,
                                              short* __restrict__ v_ds,
                                              long op_stride,
                                              const float* __restrict__ lbufg,
                                              float* __restrict__ outp) {
  int tn = blockIdx.x;
  int tm = blockIdx.y;
  int b = blockIdx.z;
  int t = threadIdx.x;
  __shared__ short lds[4 * 64 * 72];  // 36864 B; staging + epilogue reuse
  char* glds = (char*)lds;
  short* Blp = lds + 4096;  // MODE 1 padded B base (shorts), [128][40]
  int w = t >> 6, lane = t & 63;
  int wr = w >> 1, wc = w & 1;
  int l15 = lane & 15, l4 = lane >> 4;
  int wbg = __builtin_amdgcn_readfirstlane(w) << 10;

  f32x4 acc[4][4];
  for (int m = 0; m < 4; m++)
    for (int n = 0; n < 4; n++)
      for (int j = 0; j < 4; j++) acc[m][n][j] = 0.f;

  const short* Arow = Wbf + (size_t)(tm * 128) * 256;
  const short* Brow = Xt + ((size_t)b * S_ + tn * 128) * 256;

  // staging source offsets (pre-swizzled): slot s -> r=s>>2, c=s&3,
  // global chunk = c ^ ((r>>1)&3)
  int r0 = t >> 2, c40 = t & 3;
  int sw0 = (c40 ^ ((r0 >> 1) & 3)) * 8;       // shorts
  int r1 = (t + 256) >> 2;
  int sw1 = (c40 ^ ((r1 >> 1) & 3)) * 8;

  if (MODE == 0) {
    // prologue: stage step 0 -> buf0
    gl_lds16(Arow + (size_t)r0 * 256 + sw0, glds + wbg);
    gl_lds16(Arow + (size_t)r1 * 256 + sw1, glds + 4096 + wbg);
    gl_lds16(Brow + (size_t)r0 * 256 + sw0, glds + 8192 + wbg);
    gl_lds16(Brow + (size_t)r1 * 256 + sw1, glds + 12288 + wbg);
    asm volatile("s_waitcnt vmcnt(0)" ::: "memory");
    __builtin_amdgcn_s_barrier();
    asm volatile("" ::: "memory");
    for (int step = 0; step < 8; step++) {
      char* cb = glds + ((step & 1) << 14);
      if (step + 1 < 8) {  // stage next step into the other buffer (top-issue)
        char* nb = glds + (((step + 1) & 1) << 14);
        int kk = (step + 1) * 32;
        gl_lds16(Arow + (size_t)r0 * 256 + kk + sw0, nb + wbg);
        gl_lds16(Arow + (size_t)r1 * 256 + kk + sw1, nb + 4096 + wbg);
        gl_lds16(Brow + (size_t)r0 * 256 + kk + sw0, nb + 8192 + wbg);
        gl_lds16(Brow + (size_t)r1 * 256 + kk + sw1, nb + 12288 + wbg);
      }
      short8 af[4], bf[4];
      for (int mt = 0; mt < 4; mt++) {
        int row = wr * 64 + mt * 16 + l15;
        af[mt] = *reinterpret_cast<short8*>(cb + row * 64 + ((l4 ^ ((row >> 1) & 3)) << 4));
      }
      for (int nt = 0; nt < 4; nt++) {
        int row = wc * 64 + nt * 16 + l15;
        bf[nt] = *reinterpret_cast<short8*>(cb + 8192 + row * 64 + ((l4 ^ ((row >> 1) & 3)) << 4));
      }
      for (int mt = 0; mt < 4; mt++)
        for (int nt = 0; nt < 4; nt++)
          acc[mt][nt] =
              __builtin_amdgcn_mfma_f32_16x16x32_bf16(af[mt], bf[nt], acc[mt][nt], 0, 0, 0);
      if (step + 1 < 8) {
        asm volatile("s_waitcnt vmcnt(0)" ::: "memory");  // next tile landed
        __builtin_amdgcn_s_barrier();
        asm volatile("" ::: "memory");
      }
    }
  } else {
    for (int kk = 0; kk < 256; kk += 32) {
      __syncthreads();  // previous tile fully consumed
      gl_lds16(Arow + (size_t)r0 * 256 + kk + sw0, glds + wbg);
      gl_lds16(Arow + (size_t)r1 * 256 + kk + sw1, glds + 4096 + wbg);
      for (int i = 0; i < 2; i++) {
        int cch = t + i * 256;
        int r = cch >> 2, c4 = cch & 3;
        int c = kk + c4 * 8;
        int bh2 = b * 4 + (c >> 6);
        int d = c & 63;
        int s_glob = tn * 128 + r;
        size_t ro = ((size_t)bh2 * S_ + s_glob) * HD_ + d;
        float a8[8] = {0.f, 0.f, 0.f, 0.f, 0.f, 0.f, 0.f, 0.f};
        float l = 0.f;
#pragma unroll
        for (int i2 = 0; i2 < NSP; i2++) {
          short8 pv = *reinterpret_cast<const short8*>(Xt + (size_t)i2 * op_stride + ro);
#pragma unroll
          for (int j = 0; j < 8; j++) a8[j] += bf2f(pv[j]);
          l += lbufg[(size_t)(i2 * 16 + bh2) * S_ + s_glob];
        }
        float inv = 1.f / l;
        short8 vbv;
#pragma unroll
        for (int j = 0; j < 8; j++) vbv[j] = f2bf(a8[j] * inv);
        *reinterpret_cast<short8*>(&Blp[r * 40 + c4 * 8]) = vbv;
      }
      asm volatile("s_waitcnt vmcnt(0)" ::: "memory");
      __syncthreads();

      short8 af[4], bf[4];
      for (int mt = 0; mt < 4; mt++) {
        int row = wr * 64 + mt * 16 + l15;
        af[mt] = *reinterpret_cast<short8*>(glds + row * 64 + ((l4 ^ ((row >> 1) & 3)) << 4));
      }
      for (int nt = 0; nt < 4; nt++) {
        int row = wc * 64 + nt * 16 + l15;
        bf[nt] = *reinterpret_cast<short8*>(&Blp[row * 40 + l4 * 8]);
      }
      for (int mt = 0; mt < 4; mt++)
        for (int nt = 0; nt < 4; nt++)
          acc[mt][nt] =
              __builtin_amdgcn_mfma_f32_16x16x32_bf16(af[mt], bf[nt], acc[mt][nt], 0, 0, 0);
    }
  }
  __syncthreads();

  if (MODE == 0) {
    int o_base = tm * 128 + wr * 64;
    int tt = o_base >> 8;
    int h = (o_base >> 6) & 3;
    int s_base = tn * 128 + wc * 64;
    int bh = b * NH_ + h;
    if (tt == 2) {
      for (int mt = 0; mt < 4; mt++)
        for (int nt = 0; nt < 4; nt++)
          for (int i = 0; i < 4; i++) {
            int o = o_base + mt * 16 + l4 * 4 + i;
            int dd = o & 63;
            int s = s_base + nt * 16 + l15;
            float val = acc[mt][nt][i] + bias[o];
            v_ds[((size_t)bh * HD_ + dd) * S_ + s] = f2bf(val);
          }
    } else {
      float bsc = (tt == 0) ? QSC : 1.f;  // q bias scaled like W_q
      short* T = lds + w * (64 * 72);
      for (int mt = 0; mt < 4; mt++)
        for (int nt = 0; nt < 4; nt++)
          for (int i = 0; i < 4; i++) {
            int o = o_base + mt * 16 + l4 * 4 + i;
            int dd = mt * 16 + l4 * 4 + i;
            int sl = nt * 16 + l15;
            float val = acc[mt][nt][i] + bias[o] * bsc;
            T[sl * 72 + dd] = f2bf(val);
          }
      short* dst = (tt == 0) ? q_sd : k_sd;
      for (int it = 0; it < 8; it++) {
        int cch = lane + it * 64;
        int sl = cch >> 3, c8 = cch & 7;
        short8 v = *reinterpret_cast<short8*>(&T[sl * 72 + c8 * 8]);
        *reinterpret_cast<short8*>(dst + ((size_t)bh * S_ + s_base + sl) * HD_ + c8 * 8) = v;
      }
    }
  } else {
    for (int mt = 0; mt < 4; mt++) {
      int o = tm * 128 + wr * 64 + mt * 16 + l4 * 4;
      for (int nt = 0; nt < 4; nt++) {
        int s = tn * 128 + wc * 64 + nt * 16 + l15;
        for (int i = 0; i < 4; i++) {
          size_t off = ((size_t)(b * C_ + o + i)) * S_ + s;
          outp[off] = acc[mt][nt][i] + bias[o + i] + xres[off];
        }
      }
    }
  }
}

// ---------------- Flash attention: 64q/wave dual-stream, triple-buffered ----
// grid 512: bid = qt*32 + bh*2 + sk. Within-wave software pipeline:
// QK half0 -> {QK half1 MFMA ∥ exp(half0)} -> pack0 -> {PV ks=0,1 ∥ exp(half1)}
// -> pack1 -> PV ks=2,3. All register-level: correctness from data deps.
__global__ __launch_bounds__(256, 2) void k_attn(const short* __restrict__ q_sd,
                                                 const short* __restrict__ k_sd,
                                                 const short* __restrict__ v_ds,
                                                 short* __restrict__ op_base,
                                                 long op_stride,
                                                 float* __restrict__ lbuf,
                                                 int ntile) {
  int bid = blockIdx.x;
  int qt = bid >> 5;
  int bh = (bid >> 1) & 15;
  int sk = bid & 1;
  int t = threadIdx.x, w = t >> 6, lane = t & 63;
  int l31 = lane & 31, hi = lane >> 5, hi8 = hi * 8;
  int qb = qt * 256 + w * 64;

  __shared__ char smem[49152];  // 3 bufs x (K 8KB + V 8KB)

  int wb = __builtin_amdgcn_readfirstlane(w) << 10;

  int r8 = t >> 3, s8 = t & 7;
  int sw8 = (s8 ^ (r8 & 7)) * 8;
  const short* kb = k_sd + ((size_t)bh * S_ + (size_t)sk * ntile * 64) * HD_;
  const short* vbg = v_ds + (size_t)bh * HD_ * S_ + sk * ntile * 64;
  int koff0 = r8 * 64 + sw8;
  int koff1 = koff0 + 32 * 64;
  size_t voff0 = (size_t)r8 * S_ + sw8;
  size_t voff1 = voff0 + (size_t)32 * S_;

#define STAGE(bsel, ti)                                                        \
  do {                                                                         \
    const short* kt_ = kb + (size_t)(ti) * (64 * HD_);                         \
    const short* vt_ = vbg + (ti) * 64;                                        \
    char* lb_ = smem + ((bsel) << 14) + wb;                                    \
    gl_lds16(kt_ + koff0, lb_);                                                \
    gl_lds16(kt_ + koff1, lb_ + 4096);                                         \
    gl_lds16(vt_ + voff0, lb_ + 8192);                                         \
    gl_lds16(vt_ + voff1, lb_ + 12288);                                        \
  } while (0)

  const short* qpA = q_sd + ((size_t)bh * S_ + qb + l31) * HD_ + hi8;
  short8 qfA[4], qfB[4];
#pragma unroll
  for (int sl = 0; sl < 4; sl++) {
    qfA[sl] = *reinterpret_cast<const short8*>(qpA + sl * 16);
    qfB[sl] = *reinterpret_cast<const short8*>(qpA + 32 * HD_ + sl * 16);
  }

  int x7 = l31 & 7;
  int rb0 = l31 * 128;

  f32x16 OA0, OA1, OB0, OB1;
#pragma unroll
  for (int r = 0; r < 16; r++) { OA0[r] = 0.f; OA1[r] = 0.f; OB0[r] = 0.f; OB1[r] = 0.f; }
  float lA = 0.f, lB = 0.f;  // lane-local; cross-half shfl deferred to epilogue

  // prologue: stage tiles 0,1 into bufs 0,1; wait tile 0 only (vmcnt(4))
  STAGE(0, 0);
  if (ntile > 1) STAGE(1, 1);
  asm volatile("s_waitcnt vmcnt(4)" ::: "memory");
  __builtin_amdgcn_s_barrier();
  asm volatile("" ::: "memory");

// pack one f32x16 (16 k-values of one k-half) into two bf16 B-fragments
#define MKPA2(pa0, pa1, s)                                                     \
  do {                                                                         \
    unsigned c0 = pkbf(s[0], s[1]), c1 = pkbf(s[2], s[3]);                     \
    unsigned c2 = pkbf(s[4], s[5]), c3 = pkbf(s[6], s[7]);                     \
    pl32swap(c0, c2); pl32swap(c1, c3);                                        \
    uint4v u0; u0[0] = c0; u0[1] = c1; u0[2] = c2; u0[3] = c3;                 \
    pa0 = __builtin_bit_cast(short8, u0);                                      \
    unsigned c4 = pkbf(s[8], s[9]), c5 = pkbf(s[10], s[11]);                   \
    unsigned c6 = pkbf(s[12], s[13]), c7 = pkbf(s[14], s[15]);                 \
    pl32swap(c4, c6); pl32swap(c5, c7);                                        \
    uint4v u1; u1[0] = c4; u1[1] = c5; u1[2] = c6; u1[3] = c7;                 \
    pa1 = __builtin_bit_cast(short8, u1);                                      \
  } while (0)

  int cs = 0;  // current buffer selector (rotates 0,1,2)
  for (int it = 0; it < ntile; it++) {
    char* cur = smem + (cs << 14);
    int ns = (cs == 2) ? 0 : cs + 1;
    int ps = (cs == 0) ? 2 : cs - 1;  // (cs+2)%3: consumed at it-1, safe target
    if (it + 2 < ntile) STAGE(ps, it + 2);

    // ---- QK half0: k-rows 0..31 (kf0) ----
    f32x16 sA0, sB0;
#pragma unroll
    for (int r = 0; r < 16; r++) { sA0[r] = 0.f; sB0[r] = 0.f; }
    __builtin_amdgcn_s_setprio(1);
#pragma unroll
    for (int sl = 0; sl < 4; sl++) {
      int so = ((sl * 2 + hi) ^ x7) << 4;
      short8 kf0 = *reinterpret_cast<short8*>(cur + rb0 + so);
      sA0 = __builtin_amdgcn_mfma_f32_32x32x16_bf16(kf0, qfA[sl], sA0, 0, 0, 0);
      sB0 = __builtin_amdgcn_mfma_f32_32x32x16_bf16(kf0, qfB[sl], sB0, 0, 0, 0);
    }

    // ---- QK half1 (kf1) with exp(half0) interleaved ----
    f32x16 sA1, sB1;
#pragma unroll
    for (int r = 0; r < 16; r++) { sA1[r] = 0.f; sB1[r] = 0.f; }
#pragma unroll
    for (int sl = 0; sl < 4; sl++) {
      int so = ((sl * 2 + hi) ^ x7) << 4;
      short8 kf1 = *reinterpret_cast<short8*>(cur + 4096 + rb0 + so);
      sA1 = __builtin_amdgcn_mfma_f32_32x32x16_bf16(kf1, qfA[sl], sA1, 0, 0, 0);
      sB1 = __builtin_amdgcn_mfma_f32_32x32x16_bf16(kf1, qfB[sl], sB1, 0, 0, 0);
#pragma unroll
      for (int j = 0; j < 4; j++) {
        sA0[sl * 4 + j] = EXP2(sA0[sl * 4 + j]);
        sB0[sl * 4 + j] = EXP2(sB0[sl * 4 + j]);
      }
    }
    __builtin_amdgcn_s_setprio(0);

    // ---- sums(half0) + pack(half0) ----
    {
      float a0 = 0.f, a1 = 0.f, a2 = 0.f, a3 = 0.f;
      float b0 = 0.f, b1 = 0.f, b2 = 0.f, b3 = 0.f;
#pragma unroll
      for (int r = 0; r < 16; r += 4) {
        a0 += sA0[r]; a1 += sA0[r + 1]; a2 += sA0[r + 2]; a3 += sA0[r + 3];
        b0 += sB0[r]; b1 += sB0[r + 1]; b2 += sB0[r + 2]; b3 += sB0[r + 3];
      }
      lA += (a0 + a1) + (a2 + a3);
      lB += (b0 + b1) + (b2 + b3);
    }
    short8 paA0, paA1, paB0, paB1;
    MKPA2(paA0, paA1, sA0);
    MKPA2(paB0, paB1, sB0);

    // ---- PV ks=0,1 with exp(half1) interleaved ----
    __builtin_amdgcn_s_setprio(1);
#pragma unroll
    for (int ks = 0; ks < 2; ks++) {
      int so = ((ks * 2 + hi) ^ x7) << 4;
      short8 vf0 = *reinterpret_cast<short8*>(cur + 8192 + rb0 + so);
      short8 vf1 = *reinterpret_cast<short8*>(cur + 12288 + rb0 + so);
      short8 pA = ks ? paA1 : paA0;
      short8 pB = ks ? paB1 : paB0;
      OA0 = __builtin_amdgcn_mfma_f32_32x32x16_bf16(vf0, pA, OA0, 0, 0, 0);
      OB0 = __builtin_amdgcn_mfma_f32_32x32x16_bf16(vf0, pB, OB0, 0, 0, 0);
      OA1 = __builtin_amdgcn_mfma_f32_32x32x16_bf16(vf1, pA, OA1, 0, 0, 0);
      OB1 = __builtin_amdgcn_mfma_f32_32x32x16_bf16(vf1, pB, OB1, 0, 0, 0);
#pragma unroll
      for (int j = 0; j < 8; j++) {
        sA1[ks * 8 + j] = EXP2(sA1[ks * 8 + j]);
        sB1[ks * 8 + j] = EXP2(sB1[ks * 8 + j]);
      }
    }
    __builtin_amdgcn_s_setprio(0);

    // ---- sums(half1) + pack(half1) ----
    {
      float a0 = 0.f, a1 = 0.f, a2 = 0.f, a3 = 0.f;
      float b0 = 0.f, b1 = 0.f, b2 = 0.f, b3 = 0.f;
#pragma unroll
      for (int r = 0; r < 16; r += 4) {
        a0 += sA1[r]; a1 += sA1[r + 1]; a2 += sA1[r + 2]; a3 += sA1[r + 3];
        b0 += sB1[r]; b1 += sB1[r + 1]; b2 += sB1[r + 2]; b3 += sB1[r + 3];
      }
      lA += (a0 + a1) + (a2 + a3);
      lB += (b0 + b1) + (b2 + b3);
    }
    short8 paA2, paA3, paB2, paB3;
    MKPA2(paA2, paA3, sA1);
    MKPA2(paB2, paB3, sB1);

    // ---- PV ks=2,3 ----
    __builtin_amdgcn_s_setprio(1);
#pragma unroll
    for (int ks = 2; ks < 4; ks++) {
      int so = ((ks * 2 + hi) ^ x7) << 4;
      short8 vf0 = *reinterpret_cast<short8*>(cur + 8192 + rb0 + so);
      short8 vf1 = *reinterpret_cast<short8*>(cur + 12288 + rb0 + so);
      short8 pA = (ks == 2) ? paA2 : paA3;
      short8 pB = (ks == 2) ? paB2 : paB3;
      OA0 = __builtin_amdgcn_mfma_f32_32x32x16_bf16(vf0, pA, OA0, 0, 0, 0);
      OB0 = __builtin_amdgcn_mfma_f32_32x32x16_bf16(vf0, pB, OB0, 0, 0, 0);
      OA1 = __builtin_amdgcn_mfma_f32_32x32x16_bf16(vf1, pA, OA1, 0, 0, 0);
      OB1 = __builtin_amdgcn_mfma_f32_32x32x16_bf16(vf1, pB, OB1, 0, 0, 0);
    }
    __builtin_amdgcn_s_setprio(0);

    // single barrier per tile: own stage for it+2 in flight (vmcnt 4),
    // it+1's loads complete (each wave), then all waves rendezvous.
    if (it + 1 < ntile) {
      if (it + 2 < ntile)
        asm volatile("s_waitcnt vmcnt(4)" ::: "memory");
      else
        asm volatile("s_waitcnt vmcnt(0)" ::: "memory");
      __builtin_amdgcn_s_barrier();
      asm volatile("" ::: "memory");
    }
    cs = ns;
  }

  // ---- finalize l (both k-halves via lane^32), write O + l ----
  lA += __shfl_xor(lA, 32, 64);
  lB += __shfl_xor(lB, 32, 64);
  short* optrA = op_base + (size_t)sk * op_stride + ((size_t)bh * S_ + qb + l31) * HD_;
  short* optrB = optrA + 32 * HD_;
#pragma unroll
  for (int qd = 0; qd < 4; qd++) {
    short4v a0, a1, b0v, b1v;
#pragma unroll
    for (int i = 0; i < 4; i++) {
      a0[i] = f2bf(OA0[qd * 4 + i]);
      a1[i] = f2bf(OA1[qd * 4 + i]);
      b0v[i] = f2bf(OB0[qd * 4 + i]);
      b1v[i] = f2bf(OB1[qd * 4 + i]);
    }
    int d0 = qd * 8 + hi * 4;
    *reinterpret_cast<short4v*>(optrA + d0) = a0;
    *reinterpret_cast<short4v*>(optrA + 32 + d0) = a1;
    *reinterpret_cast<short4v*>(optrB + d0) = b0v;
    *reinterpret_cast<short4v*>(optrB + 32 + d0) = b1v;
  }
  if (hi == 0) {
    lbuf[(size_t)(sk * 16 + bh) * S_ + qb + l31] = lA;
    lbuf[(size_t)(sk * 16 + bh) * S_ + qb + 32 + l31] = lB;
  }
#undef STAGE
#undef MKPA2
}

extern "C" void kernel_launch(void* const* d_in, const int* in_sizes, int n_in,
                              void* d_out, int out_size, void* d_ws, size_t ws_size,
                              hipStream_t stream) {
  const float* x      = (const float*)d_in[0];
  const float* gn_w   = (const float*)d_in[1];
  const float* gn_b   = (const float*)d_in[2];
  const float* qkv_w  = (const float*)d_in[3];
  const float* qkv_b  = (const float*)d_in[4];
  const float* proj_w = (const float*)d_in[5];
  const float* proj_b = (const float*)d_in[6];
  char* ws = (char*)d_ws;
  float* part  = (float*)(ws + 2048);      // 512 floats
  short* wqkv  = (short*)(ws + 4096);
  short* wproj = (short*)(ws + 397312);
  short* xnt   = (short*)(ws + 528384);    // [4][4096][256] bf16 (reused as op0)
  short* q_sd  = (short*)(ws + 8916992);
  short* k_sd  = (short*)(ws + 17305600);
  short* v_ds  = (short*)(ws + 25694208);
  short* op_base = xnt;                    // xnt dead after gemm<0>
  long op_stride = (42471424 - 528384) / 2;  // op1 at ws+42471424
  float* lbuf  = (float*)(ws + 50860032);  // [2][16][4096] f32
  float* outp  = (float*)d_out;

  k_pre<<<256, 256, 0, stream>>>(x, qkv_w, proj_w, part, wqkv, wproj);
  k_gn_apply<<<dim3(64, 4, 4), 256, 0, stream>>>(x, gn_w, gn_b, part, xnt);
  k_gemm<0, 0><<<dim3(32, 6, 4), 256, 0, stream>>>(wqkv, xnt, qkv_b, nullptr, q_sd, k_sd, v_ds,
                                                   0, nullptr, nullptr);
  k_attn<<<512, 256, 0, stream>>>(q_sd, k_sd, v_ds, op_base, op_stride, lbuf, 32);
  k_gemm<1, 2><<<dim3(32, 2, 4), 256, 0, stream>>>(wproj, op_base, proj_b, x, nullptr, nullptr,
                                                   nullptr, op_stride, lbuf, outp);
}

// Round 18
// 122.901 us; speedup vs baseline: 1.0692x; 1.0188x over previous
//
#include <hip/hip_runtime.h>
#include <hip/hip_bf16.h>

#define B_ 4
#define C_ 256
#define S_ 4096
#define NH_ 4
#define HD_ 64
#define LOG2E 1.4426950408889634f
#define QSC 0.18033688011112042f  // 0.125 * log2(e), folded into W_q

typedef __attribute__((ext_vector_type(8))) short short8;
typedef __attribute__((ext_vector_type(4))) short short4v;
typedef __attribute__((ext_vector_type(4))) float f32x4;
typedef __attribute__((ext_vector_type(16))) float f32x16;
typedef __attribute__((ext_vector_type(4))) unsigned uint4v;

static __device__ __forceinline__ short f2bf(float f) {
  unsigned u = __builtin_bit_cast(unsigned, f);
  u += 0x7fffu + ((u >> 16) & 1u);
  return (short)(u >> 16);
}
static __device__ __forceinline__ float bf2f(short h) {
  unsigned u = ((unsigned)(unsigned short)h) << 16;
  return __builtin_bit_cast(float, u);
}

#if __has_builtin(__builtin_amdgcn_exp2f)
#define EXP2(x) __builtin_amdgcn_exp2f(x)
#else
#define EXP2(x) exp2f(x)
#endif

static __device__ __forceinline__ unsigned pkbf(float a, float b) {
  unsigned r;
  asm("v_cvt_pk_bf16_f32 %0, %1, %2" : "=v"(r) : "v"(a), "v"(b));
  return r;
}
static __device__ __forceinline__ void pl32swap(unsigned& a, unsigned& b) {
  asm volatile("v_permlane32_swap_b32 %0, %1" : "+v"(a), "+v"(b));
}
// async global->LDS, 16B per lane; lds dest = wave-uniform base + lane*16
static __device__ __forceinline__ void gl_lds16(const short* g, char* l) {
  __builtin_amdgcn_global_load_lds(
      (const __attribute__((address_space(1))) void*)g,
      (__attribute__((address_space(3))) void*)l, 16, 0, 0);
}

// ---------------- k_pre: GroupNorm partial sums + weight convert ------------
__global__ __launch_bounds__(256) void k_pre(const float* __restrict__ x,
                                             const float* __restrict__ wq,
                                             const float* __restrict__ wp,
                                             float* __restrict__ part,
                                             short* __restrict__ oq,
                                             short* __restrict__ op) {
  int t = threadIdx.x;
  const float* p = x + (size_t)blockIdx.x * 16384;
  float s = 0.f, ss = 0.f;
  const float4* p4 = reinterpret_cast<const float4*>(p);
  for (int i = t; i < 4096; i += 256) {
    float4 v = p4[i];
    s += v.x + v.y + v.z + v.w;
    ss += v.x * v.x + v.y * v.y + v.z * v.z + v.w * v.w;
  }
  for (int m = 1; m < 64; m <<= 1) {
    s += __shfl_xor(s, m, 64);
    ss += __shfl_xor(ss, m, 64);
  }
  __shared__ float rs[4], rss[4];
  int w = t >> 6;
  if ((t & 63) == 0) { rs[w] = s; rss[w] = ss; }
  {
    int i = (blockIdx.x * 256 + t) * 4;
    const int n1 = 768 * 256;
    float sc = 1.f;
    const float* src;
    short* dst;
    if (i < n1) {
      src = wq + i; dst = oq + i;
      if (i < 256 * 256) sc = QSC;
    } else {
      src = wp + (i - n1); dst = op + (i - n1);
    }
    float4 v = *reinterpret_cast<const float4*>(src);
    short4v o;
    o[0] = f2bf(v.x * sc); o[1] = f2bf(v.y * sc);
    o[2] = f2bf(v.z * sc); o[3] = f2bf(v.w * sc);
    *reinterpret_cast<short4v*>(dst) = o;
  }
  __syncthreads();
  if (t == 0) {
    part[2 * blockIdx.x] = rs[0] + rs[1] + rs[2] + rs[3];
    part[2 * blockIdx.x + 1] = rss[0] + rss[1] + rss[2] + rss[3];
  }
}

// ---------------- GN apply + transpose (stats finalized in-block) -----------
__global__ __launch_bounds__(256) void k_gn_apply(const float* __restrict__ x,
                                                  const float* __restrict__ gw,
                                                  const float* __restrict__ gb,
                                                  const float* __restrict__ part,
                                                  short* __restrict__ xnt) {
  int st = blockIdx.x;
  int ct = blockIdx.y;
  int b = blockIdx.z;
  int t = threadIdx.x;
  __shared__ short T[64 * 72];
  __shared__ float smu[2], sri[2];
  int c0 = ct * 64, s0 = st * 64;
  if (t < 2) {
    int g = (c0 >> 5) + t;
    int base = b * 64 + g * 8;
    float s = 0.f, ss = 0.f;
    for (int j = 0; j < 8; j++) {
      s += part[2 * (base + j)];
      ss += part[2 * (base + j) + 1];
    }
    float inv = 1.f / (32.f * S_);
    float mu = s * inv;
    float var = ss * inv - mu * mu;
    smu[t] = mu;
    sri[t] = rsqrtf(var + 1e-5f);
  }
  __syncthreads();
  int r4 = t >> 4;
  int f4 = t & 15;
  for (int p = 0; p < 4; p++) {
    int r = p * 16 + r4;
    int c = c0 + r;
    int gl = r >> 5;
    float mu = smu[gl];
    float ri = sri[gl];
    float A = gw[c] * ri;
    float Bb = gb[c] - mu * A;
    float4 v = *reinterpret_cast<const float4*>(x + ((size_t)(b * C_ + c)) * S_ + s0 + f4 * 4);
    int sb = f4 * 4;
    T[(sb + 0) * 72 + r] = f2bf(v.x * A + Bb);
    T[(sb + 1) * 72 + r] = f2bf(v.y * A + Bb);
    T[(sb + 2) * 72 + r] = f2bf(v.z * A + Bb);
    T[(sb + 3) * 72 + r] = f2bf(v.w * A + Bb);
  }
  __syncthreads();
  for (int it = 0; it < 2; it++) {
    int cch = t + it * 256;
    int sl = cch >> 3, c8 = cch & 7;
    short8 v = *reinterpret_cast<short8*>(&T[sl * 72 + c8 * 8]);
    *reinterpret_cast<short8*>(xnt + ((size_t)(b * S_ + s0 + sl)) * C_ + c0 + c8 * 8) = v;
  }
}

// ---------------- GEMM (TN, bf16 MFMA) ----------------
// MODE 0: qkv — A and B both gl_lds-staged, double-buffered, 1 barrier/step.
// MODE 1: proj — A gl_lds + B merge-compute, BOTH double-buffered,
//   1 __syncthreads per step (merge VALU hides under MFMAs).
template <int MODE, int NSP>
__global__ __launch_bounds__(256) void k_gemm(const short* __restrict__ Wbf,
                                              const short* __restrict__ Xt,
                                              const float* __restrict__ bias,
                                              const float* __restrict__ xres,
                                              short* __restrict__ q_sd,
                                              short* __restrict__ k_sd,
                                              short* __restrict__ v_ds,
                                              long op_stride,
                                              const float* __restrict__ lbufg,
                                              float* __restrict__ outp) {
  int tn = blockIdx.x;
  int tm = blockIdx.y;
  int b = blockIdx.z;
  int t = threadIdx.x;
  __shared__ short lds[4 * 64 * 72];  // 36864 B; staging + epilogue reuse
  char* glds = (char*)lds;
  int w = t >> 6, lane = t & 63;
  int wr = w >> 1, wc = w & 1;
  int l15 = lane & 15, l4 = lane >> 4;
  int wbg = __builtin_amdgcn_readfirstlane(w) << 10;

  f32x4 acc[4][4];
  for (int m = 0; m < 4; m++)
    for (int n = 0; n < 4; n++)
      for (int j = 0; j < 4; j++) acc[m][n][j] = 0.f;

  const short* Arow = Wbf + (size_t)(tm * 128) * 256;
  const short* Brow = Xt + ((size_t)b * S_ + tn * 128) * 256;

  // staging source offsets (pre-swizzled): slot s -> r=s>>2, c=s&3,
  // global chunk = c ^ ((r>>1)&3)
  int r0 = t >> 2, c40 = t & 3;
  int sw0 = (c40 ^ ((r0 >> 1) & 3)) * 8;       // shorts
  int r1 = (t + 256) >> 2;
  int sw1 = (c40 ^ ((r1 >> 1) & 3)) * 8;

  if (MODE == 0) {
    // prologue: stage step 0 -> buf0
    gl_lds16(Arow + (size_t)r0 * 256 + sw0, glds + wbg);
    gl_lds16(Arow + (size_t)r1 * 256 + sw1, glds + 4096 + wbg);
    gl_lds16(Brow + (size_t)r0 * 256 + sw0, glds + 8192 + wbg);
    gl_lds16(Brow + (size_t)r1 * 256 + sw1, glds + 12288 + wbg);
    asm volatile("s_waitcnt vmcnt(0)" ::: "memory");
    __builtin_amdgcn_s_barrier();
    asm volatile("" ::: "memory");
    for (int step = 0; step < 8; step++) {
      char* cb = glds + ((step & 1) << 14);
      if (step + 1 < 8) {  // stage next step into the other buffer (top-issue)
        char* nb = glds + (((step + 1) & 1) << 14);
        int kk = (step + 1) * 32;
        gl_lds16(Arow + (size_t)r0 * 256 + kk + sw0, nb + wbg);
        gl_lds16(Arow + (size_t)r1 * 256 + kk + sw1, nb + 4096 + wbg);
        gl_lds16(Brow + (size_t)r0 * 256 + kk + sw0, nb + 8192 + wbg);
        gl_lds16(Brow + (size_t)r1 * 256 + kk + sw1, nb + 12288 + wbg);
      }
      short8 af[4], bf[4];
      for (int mt = 0; mt < 4; mt++) {
        int row = wr * 64 + mt * 16 + l15;
        af[mt] = *reinterpret_cast<short8*>(cb + row * 64 + ((l4 ^ ((row >> 1) & 3)) << 4));
      }
      for (int nt = 0; nt < 4; nt++) {
        int row = wc * 64 + nt * 16 + l15;
        bf[nt] = *reinterpret_cast<short8*>(cb + 8192 + row * 64 + ((l4 ^ ((row >> 1) & 3)) << 4));
      }
      for (int mt = 0; mt < 4; mt++)
        for (int nt = 0; nt < 4; nt++)
          acc[mt][nt] =
              __builtin_amdgcn_mfma_f32_16x16x32_bf16(af[mt], bf[nt], acc[mt][nt], 0, 0, 0);
      if (step + 1 < 8) {
        asm volatile("s_waitcnt vmcnt(0)" ::: "memory");  // next tile landed
        __builtin_amdgcn_s_barrier();
        asm volatile("" ::: "memory");
      }
    }
  } else {
    // A bufs: bytes [0,8192) and [8192,16384); B bufs (padded [128][40]):
    // shorts at 8192 and 8192+5120 (bytes 16384..36863)
    short* Blp0 = lds + 8192;
    short* Blp1 = lds + 8192 + 5120;
#define MERGE_B(kk_, dstB)                                                     \
    do {                                                                       \
      for (int i = 0; i < 2; i++) {                                            \
        int cch = t + i * 256;                                                 \
        int r = cch >> 2, c4 = cch & 3;                                        \
        int c = (kk_) + c4 * 8;                                                \
        int bh2 = b * 4 + (c >> 6);                                            \
        int d = c & 63;                                                        \
        int s_glob = tn * 128 + r;                                             \
        size_t ro = ((size_t)bh2 * S_ + s_glob) * HD_ + d;                     \
        float a8[8] = {0.f, 0.f, 0.f, 0.f, 0.f, 0.f, 0.f, 0.f};                \
        float l = 0.f;                                                         \
        _Pragma("unroll") for (int i2 = 0; i2 < NSP; i2++) {                   \
          short8 pv = *reinterpret_cast<const short8*>(                        \
              Xt + (size_t)i2 * op_stride + ro);                               \
          _Pragma("unroll") for (int j = 0; j < 8; j++) a8[j] += bf2f(pv[j]);  \
          l += lbufg[(size_t)(i2 * 16 + bh2) * S_ + s_glob];                   \
        }                                                                      \
        float inv = 1.f / l;                                                   \
        short8 vbv;                                                            \
        _Pragma("unroll") for (int j = 0; j < 8; j++)                          \
            vbv[j] = f2bf(a8[j] * inv);                                        \
        *reinterpret_cast<short8*>(&(dstB)[r * 40 + c4 * 8]) = vbv;            \
      }                                                                        \
    } while (0)

    // prologue: stage A0 + merge B0
    gl_lds16(Arow + (size_t)r0 * 256 + sw0, glds + wbg);
    gl_lds16(Arow + (size_t)r1 * 256 + sw1, glds + 4096 + wbg);
    MERGE_B(0, Blp0);
    __syncthreads();
    for (int step = 0; step < 8; step++) {
      char* cbA = glds + ((step & 1) ? 8192 : 0);
      short* cbB = (step & 1) ? Blp1 : Blp0;
      if (step + 1 < 8) {
        char* nbA = glds + (((step + 1) & 1) ? 8192 : 0);
        short* nbB = ((step + 1) & 1) ? Blp1 : Blp0;
        int kk = (step + 1) * 32;
        gl_lds16(Arow + (size_t)r0 * 256 + kk + sw0, nbA + wbg);
        gl_lds16(Arow + (size_t)r1 * 256 + kk + sw1, nbA + 4096 + wbg);
        MERGE_B(kk, nbB);
      }
      short8 af[4], bf[4];
      for (int mt = 0; mt < 4; mt++) {
        int row = wr * 64 + mt * 16 + l15;
        af[mt] = *reinterpret_cast<short8*>(cbA + row * 64 + ((l4 ^ ((row >> 1) & 3)) << 4));
      }
      for (int nt = 0; nt < 4; nt++) {
        int row = wc * 64 + nt * 16 + l15;
        bf[nt] = *reinterpret_cast<short8*>(&cbB[row * 40 + l4 * 8]);
      }
      for (int mt = 0; mt < 4; mt++)
        for (int nt = 0; nt < 4; nt++)
          acc[mt][nt] =
              __builtin_amdgcn_mfma_f32_16x16x32_bf16(af[mt], bf[nt], acc[mt][nt], 0, 0, 0);
      if (step + 1 < 8) __syncthreads();
    }
#undef MERGE_B
  }
  __syncthreads();

  if (MODE == 0) {
    int o_base = tm * 128 + wr * 64;
    int tt = o_base >> 8;
    int h = (o_base >> 6) & 3;
    int s_base = tn * 128 + wc * 64;
    int bh = b * NH_ + h;
    if (tt == 2) {
      for (int mt = 0; mt < 4; mt++)
        for (int nt = 0; nt < 4; nt++)
          for (int i = 0; i < 4; i++) {
            int o = o_base + mt * 16 + l4 * 4 + i;
            int dd = o & 63;
            int s = s_base + nt * 16 + l15;
            float val = acc[mt][nt][i] + bias[o];
            v_ds[((size_t)bh * HD_ + dd) * S_ + s] = f2bf(val);
          }
    } else {
      float bsc = (tt == 0) ? QSC : 1.f;  // q bias scaled like W_q
      short* T = lds + w * (64 * 72);
      for (int mt = 0; mt < 4; mt++)
        for (int nt = 0; nt < 4; nt++)
          for (int i = 0; i < 4; i++) {
            int o = o_base + mt * 16 + l4 * 4 + i;
            int dd = mt * 16 + l4 * 4 + i;
            int sl = nt * 16 + l15;
            float val = acc[mt][nt][i] + bias[o] * bsc;
            T[sl * 72 + dd] = f2bf(val);
          }
      short* dst = (tt == 0) ? q_sd : k_sd;
      for (int it = 0; it < 8; it++) {
        int cch = lane + it * 64;
        int sl = cch >> 3, c8 = cch & 7;
        short8 v = *reinterpret_cast<short8*>(&T[sl * 72 + c8 * 8]);
        *reinterpret_cast<short8*>(dst + ((size_t)bh * S_ + s_base + sl) * HD_ + c8 * 8) = v;
      }
    }
  } else {
    for (int mt = 0; mt < 4; mt++) {
      int o = tm * 128 + wr * 64 + mt * 16 + l4 * 4;
      for (int nt = 0; nt < 4; nt++) {
        int s = tn * 128 + wc * 64 + nt * 16 + l15;
        for (int i = 0; i < 4; i++) {
          size_t off = ((size_t)(b * C_ + o + i)) * S_ + s;
          outp[off] = acc[mt][nt][i] + bias[o + i] + xres[off];
        }
      }
    }
  }
}

// ---------------- Flash attention: 64q/wave dual-stream, triple-buffered ----
// grid 512: bid = qt*32 + bh*2 + sk. l computed via ones-row MFMA:
// lacc = mfma(eA,paA*) + mfma(eB,paB*): row0 = lA, row1 = lB (hi=0 lanes).
__global__ __launch_bounds__(256, 2) void k_attn(const short* __restrict__ q_sd,
                                                 const short* __restrict__ k_sd,
                                                 const short* __restrict__ v_ds,
                                                 short* __restrict__ op_base,
                                                 long op_stride,
                                                 float* __restrict__ lbuf,
                                                 int ntile) {
  int bid = blockIdx.x;
  int qt = bid >> 5;
  int bh = (bid >> 1) & 15;
  int sk = bid & 1;
  int t = threadIdx.x, w = t >> 6, lane = t & 63;
  int l31 = lane & 31, hi = lane >> 5, hi8 = hi * 8;
  int qb = qt * 256 + w * 64;

  __shared__ char smem[49152];  // 3 bufs x (K 8KB + V 8KB)

  int wb = __builtin_amdgcn_readfirstlane(w) << 10;

  int r8 = t >> 3, s8 = t & 7;
  int sw8 = (s8 ^ (r8 & 7)) * 8;
  const short* kb = k_sd + ((size_t)bh * S_ + (size_t)sk * ntile * 64) * HD_;
  const short* vbg = v_ds + (size_t)bh * HD_ * S_ + sk * ntile * 64;
  int koff0 = r8 * 64 + sw8;
  int koff1 = koff0 + 32 * 64;
  size_t voff0 = (size_t)r8 * S_ + sw8;
  size_t voff1 = voff0 + (size_t)32 * S_;

#define STAGE(bsel, ti)                                                        \
  do {                                                                         \
    const short* kt_ = kb + (size_t)(ti) * (64 * HD_);                         \
    const short* vt_ = vbg + (ti) * 64;                                        \
    char* lb_ = smem + ((bsel) << 14) + wb;                                    \
    gl_lds16(kt_ + koff0, lb_);                                                \
    gl_lds16(kt_ + koff1, lb_ + 4096);                                         \
    gl_lds16(vt_ + voff0, lb_ + 8192);                                         \
    gl_lds16(vt_ + voff1, lb_ + 12288);                                        \
  } while (0)

  const short* qpA = q_sd + ((size_t)bh * S_ + qb + l31) * HD_ + hi8;
  short8 qfA[4], qfB[4];
#pragma unroll
  for (int sl = 0; sl < 4; sl++) {
    qfA[sl] = *reinterpret_cast<const short8*>(qpA + sl * 16);
    qfB[sl] = *reinterpret_cast<const short8*>(qpA + 32 * HD_ + sl * 16);
  }

  // ones-row A-fragments for the l-MFMA: eA = ones in row 0, eB in row 1
  const short one_bf = (short)0x3F80;
  short8 eA, eB;
#pragma unroll
  for (int j = 0; j < 8; j++) {
    eA[j] = (l31 == 0) ? one_bf : (short)0;
    eB[j] = (l31 == 1) ? one_bf : (short)0;
  }

  int x7 = l31 & 7;
  int rb0 = l31 * 128;

  f32x16 OA0, OA1, OB0, OB1, lacc;
#pragma unroll
  for (int r = 0; r < 16; r++) {
    OA0[r] = 0.f; OA1[r] = 0.f; OB0[r] = 0.f; OB1[r] = 0.f; lacc[r] = 0.f;
  }

  // prologue: stage tiles 0,1 into bufs 0,1; wait tile 0 only (vmcnt(4))
  STAGE(0, 0);
  if (ntile > 1) STAGE(1, 1);
  asm volatile("s_waitcnt vmcnt(4)" ::: "memory");
  __builtin_amdgcn_s_barrier();
  asm volatile("" ::: "memory");

// pack one f32x16 (16 k-values of one k-half) into two bf16 B-fragments
#define MKPA2(pa0, pa1, s)                                                     \
  do {                                                                         \
    unsigned c0 = pkbf(s[0], s[1]), c1 = pkbf(s[2], s[3]);                     \
    unsigned c2 = pkbf(s[4], s[5]), c3 = pkbf(s[6], s[7]);                     \
    pl32swap(c0, c2); pl32swap(c1, c3);                                        \
    uint4v u0; u0[0] = c0; u0[1] = c1; u0[2] = c2; u0[3] = c3;                 \
    pa0 = __builtin_bit_cast(short8, u0);                                      \
    unsigned c4 = pkbf(s[8], s[9]), c5 = pkbf(s[10], s[11]);                   \
    unsigned c6 = pkbf(s[12], s[13]), c7 = pkbf(s[14], s[15]);                 \
    pl32swap(c4, c6); pl32swap(c5, c7);                                        \
    uint4v u1; u1[0] = c4; u1[1] = c5; u1[2] = c6; u1[3] = c7;                 \
    pa1 = __builtin_bit_cast(short8, u1);                                      \
  } while (0)

  int cs = 0;  // current buffer selector (rotates 0,1,2)
  for (int it = 0; it < ntile; it++) {
    char* cur = smem + (cs << 14);
    int ns = (cs == 2) ? 0 : cs + 1;
    int ps = (cs == 0) ? 2 : cs - 1;  // (cs+2)%3: consumed at it-1, safe target
    if (it + 2 < ntile) STAGE(ps, it + 2);

    // ---- QK half0: k-rows 0..31 (kf0) ----
    f32x16 sA0, sB0;
#pragma unroll
    for (int r = 0; r < 16; r++) { sA0[r] = 0.f; sB0[r] = 0.f; }
    __builtin_amdgcn_s_setprio(1);
#pragma unroll
    for (int sl = 0; sl < 4; sl++) {
      int so = ((sl * 2 + hi) ^ x7) << 4;
      short8 kf0 = *reinterpret_cast<short8*>(cur + rb0 + so);
      sA0 = __builtin_amdgcn_mfma_f32_32x32x16_bf16(kf0, qfA[sl], sA0, 0, 0, 0);
      sB0 = __builtin_amdgcn_mfma_f32_32x32x16_bf16(kf0, qfB[sl], sB0, 0, 0, 0);
    }

    // ---- QK half1 (kf1) with exp(half0) interleaved ----
    f32x16 sA1, sB1;
#pragma unroll
    for (int r = 0; r < 16; r++) { sA1[r] = 0.f; sB1[r] = 0.f; }
#pragma unroll
    for (int sl = 0; sl < 4; sl++) {
      int so = ((sl * 2 + hi) ^ x7) << 4;
      short8 kf1 = *reinterpret_cast<short8*>(cur + 4096 + rb0 + so);
      sA1 = __builtin_amdgcn_mfma_f32_32x32x16_bf16(kf1, qfA[sl], sA1, 0, 0, 0);
      sB1 = __builtin_amdgcn_mfma_f32_32x32x16_bf16(kf1, qfB[sl], sB1, 0, 0, 0);
#pragma unroll
      for (int j = 0; j < 4; j++) {
        sA0[sl * 4 + j] = EXP2(sA0[sl * 4 + j]);
        sB0[sl * 4 + j] = EXP2(sB0[sl * 4 + j]);
      }
    }
    __builtin_amdgcn_s_setprio(0);

    // ---- pack(half0) + l-MFMA(half0) ----
    short8 paA0, paA1, paB0, paB1;
    MKPA2(paA0, paA1, sA0);
    MKPA2(paB0, paB1, sB0);
    lacc = __builtin_amdgcn_mfma_f32_32x32x16_bf16(eA, paA0, lacc, 0, 0, 0);
    lacc = __builtin_amdgcn_mfma_f32_32x32x16_bf16(eA, paA1, lacc, 0, 0, 0);
    lacc = __builtin_amdgcn_mfma_f32_32x32x16_bf16(eB, paB0, lacc, 0, 0, 0);
    lacc = __builtin_amdgcn_mfma_f32_32x32x16_bf16(eB, paB1, lacc, 0, 0, 0);

    // ---- PV ks=0,1 with exp(half1) interleaved ----
    __builtin_amdgcn_s_setprio(1);
#pragma unroll
    for (int ks = 0; ks < 2; ks++) {
      int so = ((ks * 2 + hi) ^ x7) << 4;
      short8 vf0 = *reinterpret_cast<short8*>(cur + 8192 + rb0 + so);
      short8 vf1 = *reinterpret_cast<short8*>(cur + 12288 + rb0 + so);
      short8 pA = ks ? paA1 : paA0;
      short8 pB = ks ? paB1 : paB0;
      OA0 = __builtin_amdgcn_mfma_f32_32x32x16_bf16(vf0, pA, OA0, 0, 0, 0);
      OB0 = __builtin_amdgcn_mfma_f32_32x32x16_bf16(vf0, pB, OB0, 0, 0, 0);
      OA1 = __builtin_amdgcn_mfma_f32_32x32x16_bf16(vf1, pA, OA1, 0, 0, 0);
      OB1 = __builtin_amdgcn_mfma_f32_32x32x16_bf16(vf1, pB, OB1, 0, 0, 0);
#pragma unroll
      for (int j = 0; j < 8; j++) {
        sA1[ks * 8 + j] = EXP2(sA1[ks * 8 + j]);
        sB1[ks * 8 + j] = EXP2(sB1[ks * 8 + j]);
      }
    }
    __builtin_amdgcn_s_setprio(0);

    // ---- pack(half1) + l-MFMA(half1) ----
    short8 paA2, paA3, paB2, paB3;
    MKPA2(paA2, paA3, sA1);
    MKPA2(paB2, paB3, sB1);
    lacc = __builtin_amdgcn_mfma_f32_32x32x16_bf16(eA, paA2, lacc, 0, 0, 0);
    lacc = __builtin_amdgcn_mfma_f32_32x32x16_bf16(eA, paA3, lacc, 0, 0, 0);
    lacc = __builtin_amdgcn_mfma_f32_32x32x16_bf16(eB, paB2, lacc, 0, 0, 0);
    lacc = __builtin_amdgcn_mfma_f32_32x32x16_bf16(eB, paB3, lacc, 0, 0, 0);

    // ---- PV ks=2,3 ----
    __builtin_amdgcn_s_setprio(1);
#pragma unroll
    for (int ks = 2; ks < 4; ks++) {
      int so = ((ks * 2 + hi) ^ x7) << 4;
      short8 vf0 = *reinterpret_cast<short8*>(cur + 8192 + rb0 + so);
      short8 vf1 = *reinterpret_cast<short8*>(cur + 12288 + rb0 + so);
      short8 pA = (ks == 2) ? paA2 : paA3;
      short8 pB = (ks == 2) ? paB2 : paB3;
      OA0 = __builtin_amdgcn_mfma_f32_32x32x16_bf16(vf0, pA, OA0, 0, 0, 0);
      OB0 = __builtin_amdgcn_mfma_f32_32x32x16_bf16(vf0, pB, OB0, 0, 0, 0);
      OA1 = __builtin_amdgcn_mfma_f32_32x32x16_bf16(vf1, pA, OA1, 0, 0, 0);
      OB1 = __builtin_amdgcn_mfma_f32_32x32x16_bf16(vf1, pB, OB1, 0, 0, 0);
    }
    __builtin_amdgcn_s_setprio(0);

    // single barrier per tile: own stage for it+2 in flight (vmcnt 4),
    // it+1's loads complete (each wave), then all waves rendezvous.
    if (it + 1 < ntile) {
      if (it + 2 < ntile)
        asm volatile("s_waitcnt vmcnt(4)" ::: "memory");
      else
        asm volatile("s_waitcnt vmcnt(0)" ::: "memory");
      __builtin_amdgcn_s_barrier();
      asm volatile("" ::: "memory");
    }
    cs = ns;
  }

  // ---- write O (bf16) + l (lacc row0 = lA, row1 = lB, on hi=0 lanes) ----
  short* optrA = op_base + (size_t)sk * op_stride + ((size_t)bh * S_ + qb + l31) * HD_;
  short* optrB = optrA + 32 * HD_;
#pragma unroll
  for (int qd = 0; qd < 4; qd++) {
    short4v a0, a1, b0v, b1v;
#pragma unroll
    for (int i = 0; i < 4; i++) {
      a0[i] = f2bf(OA0[qd * 4 + i]);
      a1[i] = f2bf(OA1[qd * 4 + i]);
      b0v[i] = f2bf(OB0[qd * 4 + i]);
      b1v[i] = f2bf(OB1[qd * 4 + i]);
    }
    int d0 = qd * 8 + hi * 4;
    *reinterpret_cast<short4v*>(optrA + d0) = a0;
    *reinterpret_cast<short4v*>(optrA + 32 + d0) = a1;
    *reinterpret_cast<short4v*>(optrB + d0) = b0v;
    *reinterpret_cast<short4v*>(optrB + 32 + d0) = b1v;
  }
  if (hi == 0) {
    lbuf[(size_t)(sk * 16 + bh) * S_ + qb + l31] = lacc[0];
    lbuf[(size_t)(sk * 16 + bh) * S_ + qb + 32 + l31] = lacc[1];
  }
#undef STAGE
#undef MKPA2
}

extern "C" void kernel_launch(void* const* d_in, const int* in_sizes, int n_in,
                              void* d_out, int out_size, void* d_ws, size_t ws_size,
                              hipStream_t stream) {
  const float* x      = (const float*)d_in[0];
  const float* gn_w   = (const float*)d_in[1];
  const float* gn_b   = (const float*)d_in[2];
  const float* qkv_w  = (const float*)d_in[3];
  const float* qkv_b  = (const float*)d_in[4];
  const float* proj_w = (const float*)d_in[5];
  const float* proj_b = (const float*)d_in[6];
  char* ws = (char*)d_ws;
  float* part  = (float*)(ws + 2048);      // 512 floats
  short* wqkv  = (short*)(ws + 4096);
  short* wproj = (short*)(ws + 397312);
  short* xnt   = (short*)(ws + 528384);    // [4][4096][256] bf16 (reused as op0)
  short* q_sd  = (short*)(ws + 8916992);
  short* k_sd  = (short*)(ws + 17305600);
  short* v_ds  = (short*)(ws + 25694208);
  short* op_base = xnt;                    // xnt dead after gemm<0>
  long op_stride = (42471424 - 528384) / 2;  // op1 at ws+42471424
  float* lbuf  = (float*)(ws + 50860032);  // [2][16][4096] f32
  float* outp  = (float*)d_out;

  k_pre<<<256, 256, 0, stream>>>(x, qkv_w, proj_w, part, wqkv, wproj);
  k_gn_apply<<<dim3(64, 4, 4), 256, 0, stream>>>(x, gn_w, gn_b, part, xnt);
  k_gemm<0, 0><<<dim3(32, 6, 4), 256, 0, stream>>>(wqkv, xnt, qkv_b, nullptr, q_sd, k_sd, v_ds,
                                                   0, nullptr, nullptr);
  k_attn<<<512, 256, 0, stream>>>(q_sd, k_sd, v_ds, op_base, op_stride, lbuf, 32);
  k_gemm<1, 2><<<dim3(32, 2, 4), 256, 0, stream>>>(wproj, op_base, proj_b, x, nullptr, nullptr,
                                                   nullptr, op_stride, lbuf, outp);
}